// Round 13
// baseline (226.756 us; speedup 1.0000x reference)
//
#include <hip/hip_runtime.h>
#include <hip/hip_bf16.h>
#include <hip/hip_fp16.h>

#define N_NODES_C 100000
#define NSCAN     102400      // N padded to 25 * 4096 for the scan
#define SCAN_BS   1024        // threads per scan block (4 elems each -> 4096/block)
#define NB_SCAN   (NSCAN / (SCAN_BS * 4))   // 25 blocks

// ---------------------------------------------------------------------------
// fp16 helpers: h_src stored as packed fp16 (uint = 2 halves)
// ---------------------------------------------------------------------------
union U2H { unsigned u; __half2 h; };

__device__ __forceinline__ __half2 addp(__half2 a, unsigned u)
{
    U2H c; c.u = u;
    return __hadd2(a, c.h);
}

__device__ __forceinline__ __half2 shfl_xor_h2(__half2 v, int m)
{
    U2H c; c.h = v;
    c.u = (unsigned)__shfl_xor((int)c.u, m, 64);
    return c.h;
}

// h_src f32 -> packed fp16 copy; row N_NODES_C is written as zeros (pad row)
__global__ __launch_bounds__(256) void convert_fp16(
    const float* __restrict__ x, uint4* __restrict__ y, int n8)
{
    int i = blockIdx.x * 256 + threadIdx.x;
    if (i >= n8 + 8) return;
    if (i >= n8) { y[i] = make_uint4(0u, 0u, 0u, 0u); return; }
    const float4* x4 = reinterpret_cast<const float4*>(x);
    float4 a = x4[i * 2 + 0];
    float4 b = x4[i * 2 + 1];
    U2H c0, c1, c2, c3;
    c0.h = __floats2half2_rn(a.x, a.y);
    c1.h = __floats2half2_rn(a.z, a.w);
    c2.h = __floats2half2_rn(b.x, b.y);
    c3.h = __floats2half2_rn(b.z, b.w);
    uint4 o;
    o.x = c0.u; o.y = c1.u; o.z = c2.u; o.w = c3.u;
    y[i] = o;
}

// ---------------------------------------------------------------------------
// CSR build (padded-to-8 segments):
// histogram(+rank) -> block scan of PADDED counts -> scan_add (+pad fill) -> fill
// ---------------------------------------------------------------------------
__global__ __launch_bounds__(256) void edge_hist(
    const int* __restrict__ dst, int* __restrict__ counts,
    int* __restrict__ rank, int n_edges)
{
    int i = blockIdx.x * 256 + threadIdx.x;
    int b4 = i * 4;
    if (b4 + 3 < n_edges) {
        int4 d = reinterpret_cast<const int4*>(dst)[i];
        int4 rk;
        rk.x = atomicAdd(&counts[d.x], 1);
        rk.y = atomicAdd(&counts[d.y], 1);
        rk.z = atomicAdd(&counts[d.z], 1);
        rk.w = atomicAdd(&counts[d.w], 1);
        reinterpret_cast<int4*>(rank)[i] = rk;
    } else {
        for (int e = b4; e < n_edges; ++e)
            rank[e] = atomicAdd(&counts[dst[e]], 1);
    }
}

__global__ __launch_bounds__(SCAN_BS) void scan_block(
    const int* __restrict__ counts, int* __restrict__ offsets,
    int* __restrict__ partials)
{
    __shared__ int sd[2][SCAN_BS];
    int t = threadIdx.x, b = blockIdx.x;
    int4 c = reinterpret_cast<const int4*>(counts)[b * SCAN_BS + t];
    int q0 = (c.x + 7) & ~7;
    int q1 = (c.y + 7) & ~7;
    int q2 = (c.z + 7) & ~7;
    int q3 = (c.w + 7) & ~7;
    int tot = q0 + q1 + q2 + q3;
    sd[0][t] = tot;
    __syncthreads();
    int pin = 0;
    #pragma unroll
    for (int off = 1; off < SCAN_BS; off <<= 1) {
        int v = sd[pin][t];
        if (t >= off) v += sd[pin][t - off];
        sd[pin ^ 1][t] = v;
        pin ^= 1;
        __syncthreads();
    }
    int incl = sd[pin][t];      // inclusive scan of per-thread padded sums
    int excl = incl - tot;
    int4 o;
    o.x = excl;
    o.y = excl + q0;
    o.z = excl + q0 + q1;
    o.w = excl + q0 + q1 + q2;
    reinterpret_cast<int4*>(offsets)[b * SCAN_BS + t] = o;
    if (t == SCAN_BS - 1) partials[b] = incl;
}

// add block bases; also fill each node's pad slots with the dummy index N
__global__ __launch_bounds__(SCAN_BS) void scan_add(
    int* __restrict__ offsets, const int* __restrict__ partials,
    const int* __restrict__ counts, int* __restrict__ edge_src)
{
    __shared__ int base_s;
    int b = blockIdx.x;
    if (threadIdx.x == 0) {
        int s = 0;
        for (int i = 0; i < b; ++i) s += partials[i];
        base_s = s;
    }
    __syncthreads();
    int i = b * SCAN_BS + threadIdx.x;
    int4 v = reinterpret_cast<int4*>(offsets)[i];
    v.x += base_s; v.y += base_s; v.z += base_s; v.w += base_s;
    reinterpret_cast<int4*>(offsets)[i] = v;
    int4 c = reinterpret_cast<const int4*>(counts)[i];
    int s, ep;
    s = v.x + c.x; ep = v.x + ((c.x + 7) & ~7); for (; s < ep; ++s) edge_src[s] = N_NODES_C;
    s = v.y + c.y; ep = v.y + ((c.y + 7) & ~7); for (; s < ep; ++s) edge_src[s] = N_NODES_C;
    s = v.z + c.z; ep = v.z + ((c.z + 7) & ~7); for (; s < ep; ++s) edge_src[s] = N_NODES_C;
    s = v.w + c.w; ep = v.w + ((c.w + 7) & ~7); for (; s < ep; ++s) edge_src[s] = N_NODES_C;
}

__global__ __launch_bounds__(256) void edge_fill(
    const int* __restrict__ src, const int* __restrict__ dst,
    const int* __restrict__ rank, const int* __restrict__ offsets,
    int* __restrict__ edge_src, int n_edges)
{
    int i = blockIdx.x * 256 + threadIdx.x;
    int b4 = i * 4;
    if (b4 + 3 < n_edges) {
        int4 s  = reinterpret_cast<const int4*>(src)[i];
        int4 d  = reinterpret_cast<const int4*>(dst)[i];
        int4 rk = reinterpret_cast<const int4*>(rank)[i];
        edge_src[offsets[d.x] + rk.x] = s.x;
        edge_src[offsets[d.y] + rk.y] = s.y;
        edge_src[offsets[d.z] + rk.z] = s.z;
        edge_src[offsets[d.w] + rk.w] = s.w;
    } else {
        for (int e = b4; e < n_edges; ++e)
            edge_src[offsets[dst[e]] + rank[e]] = src[e];
    }
}

// ---------------------------------------------------------------------------
// Gather: ONE WAVE PER NODE (100K waves -> TLP hides all gather latency).
// Lane = (slot = lane>>3, chunk = lane&7): one wave-wide load instruction
// covers 8 edges x 128 B. deg~10 -> ~2 iterations, trip count wave-uniform
// (padded-to-8 edge lists; pad index N -> zero row). 3x shfl_xor pk-add
// reduce over slots; lanes 0..7 write the fp16 mean row (128 B).
// ---------------------------------------------------------------------------
__global__ __launch_bounds__(256) void sage_gather(
    const uint4* __restrict__ hsb,      // packed fp16 h_src [(N+1)][8] uint4
    const int*   __restrict__ offsets,  // padded CSR offsets
    const int*   __restrict__ counts,   // raw degrees
    const int*   __restrict__ edge_src, // padded edge lists
    uint4*       __restrict__ meanh,    // out: fp16 mean rows [N][8] uint4
    int n_nodes)
{
    int wid  = (blockIdx.x * 256 + threadIdx.x) >> 6;   // node id (grid exact)
    int lane = threadIdx.x & 63;
    int slot = lane >> 3;
    int chunk = lane & 7;

    int e0  = offsets[wid];    // wave-uniform -> scalar loads
    int deg = counts[wid];
    int nit = (deg + 7) >> 3;

    __half2 a0, a1, a2, a3;
    {
        U2H z; z.u = 0u;
        a0 = z.h; a1 = z.h; a2 = z.h; a3 = z.h;
    }

    for (int it = 0; it < nit; ++it) {
        int s = edge_src[e0 + (it << 3) + slot];
        uint4 v = hsb[(size_t)s * 8 + chunk];
        a0 = addp(a0, v.x);
        a1 = addp(a1, v.y);
        a2 = addp(a2, v.z);
        a3 = addp(a3, v.w);
    }

    // reduce over the 8 slots (lane bits 3,4,5)
    #pragma unroll
    for (int m = 8; m < 64; m <<= 1) {
        a0 = __hadd2(a0, shfl_xor_h2(a0, m));
        a1 = __hadd2(a1, shfl_xor_h2(a1, m));
        a2 = __hadd2(a2, shfl_xor_h2(a2, m));
        a3 = __hadd2(a3, shfl_xor_h2(a3, m));
    }

    if (lane < 8) {
        float invd = 1.0f / (float)(deg > 1 ? deg : 1);
        U2H o0, o1, o2, o3;
        o0.h = __floats2half2_rn(__low2float(a0) * invd, __high2float(a0) * invd);
        o1.h = __floats2half2_rn(__low2float(a1) * invd, __high2float(a1) * invd);
        o2.h = __floats2half2_rn(__low2float(a2) * invd, __high2float(a2) * invd);
        o3.h = __floats2half2_rn(__low2float(a3) * invd, __high2float(a3) * invd);
        meanh[(size_t)wid * 8 + lane] = make_uint4(o0.u, o1.u, o2.u, o3.u);
    }
}

// ---------------------------------------------------------------------------
// GEMM epilogue: 64 nodes/block, X tile in LDS (swizzled float4):
// cols 0..15 = h_dst (f32), cols 16..31 = fp16 mean rows (unpacked).
// W streamed from global (L1-resident, 16-lane dedup). 4x4 thread tile.
// ---------------------------------------------------------------------------
__global__ __launch_bounds__(256) void sage_gemm(
    const float* __restrict__ h_dst,
    const uint4* __restrict__ meanh,    // fp16 mean rows [N][8] uint4
    const float* __restrict__ weight,   // [64][128] row-major
    const float* __restrict__ bias,     // [64]
    float*       __restrict__ out,      // [N][64]
    int n_nodes)
{
    __shared__ float4 x4[64 * 32];   // x4[r][c] at r*32 + ((c + r) & 31)

    const int t    = threadIdx.x;
    const int base = blockIdx.x * 64;

    // stage h_dst (cols 0..15): 4 float4 per thread
    #pragma unroll
    for (int q = 0; q < 4; ++q) {
        int idx = t + q * 256;        // 0..1023
        int r   = idx >> 4;
        int k4  = idx & 15;
        int g   = base + r;
        float4 xv = make_float4(0.f, 0.f, 0.f, 0.f);
        if (g < n_nodes)
            xv = reinterpret_cast<const float4*>(h_dst)[(size_t)g * 16 + k4];
        x4[r * 32 + ((k4 + r) & 31)] = xv;
    }

    // stage mean (cols 16..31): 2 uint4 per thread, unpack fp16 -> f32
    #pragma unroll
    for (int q = 0; q < 2; ++q) {
        int idx = t + q * 256;        // 0..511
        int r   = idx >> 3;
        int c8  = idx & 7;
        int g   = base + r;
        uint4 mv = make_uint4(0u, 0u, 0u, 0u);
        if (g < n_nodes)
            mv = meanh[(size_t)g * 8 + c8];
        U2H u0, u1, u2, u3;
        u0.u = mv.x; u1.u = mv.y; u2.u = mv.z; u3.u = mv.w;
        float4 lo = make_float4(__low2float(u0.h), __high2float(u0.h),
                                __low2float(u1.h), __high2float(u1.h));
        float4 hi = make_float4(__low2float(u2.h), __high2float(u2.h),
                                __low2float(u3.h), __high2float(u3.h));
        x4[r * 32 + (((16 + 2 * c8) + r) & 31)] = lo;
        x4[r * 32 + (((17 + 2 * c8) + r) & 31)] = hi;
    }
    __syncthreads();

    // GEMM: thread tile = 4 nodes x 4 outs; W streamed from global (L1)
    const int m  = t & 15;    // out-group: o0 = 4m
    const int r0 = t >> 4;    // node base: rows r0 + 16*i
    const int o0 = m * 4;

    const float4* w4g = reinterpret_cast<const float4*>(weight);
    float4 bv = reinterpret_cast<const float4*>(bias)[m];

    float acc[4][4];
    #pragma unroll
    for (int i = 0; i < 4; ++i) {
        acc[i][0] = bv.x; acc[i][1] = bv.y; acc[i][2] = bv.z; acc[i][3] = bv.w;
    }

    #pragma unroll 4
    for (int k4 = 0; k4 < 32; ++k4) {
        float4 wv[4];
        #pragma unroll
        for (int jj = 0; jj < 4; ++jj)
            wv[jj] = w4g[(o0 + jj) * 32 + k4];
        #pragma unroll
        for (int i = 0; i < 4; ++i) {
            int r = r0 + 16 * i;
            float4 xv = x4[r * 32 + ((k4 + r) & 31)];
            #pragma unroll
            for (int jj = 0; jj < 4; ++jj) {
                acc[i][jj] += xv.x * wv[jj].x + xv.y * wv[jj].y
                            + xv.z * wv[jj].z + xv.w * wv[jj].w;
            }
        }
    }

    #pragma unroll
    for (int i = 0; i < 4; ++i) {
        int g = base + r0 + 16 * i;
        if (g < n_nodes) {
            float4 ov = make_float4(acc[i][0], acc[i][1], acc[i][2], acc[i][3]);
            reinterpret_cast<float4*>(out)[(size_t)g * 16 + m] = ov;
        }
    }
}

// ---------------------------------------------------------------------------
extern "C" void kernel_launch(void* const* d_in, const int* in_sizes, int n_in,
                              void* d_out, int out_size, void* d_ws, size_t ws_size,
                              hipStream_t stream)
{
    const float* h_src  = (const float*)d_in[0];
    const float* h_dst  = (const float*)d_in[1];
    const int*   src    = (const int*)d_in[2];
    const int*   dst    = (const int*)d_in[3];
    const float* weight = (const float*)d_in[4];
    const float* bias   = (const float*)d_in[5];
    float*       out    = (float*)d_out;

    const int n_edges = in_sizes[2];
    const int n_feat  = in_sizes[0];   // N*64 floats

    // workspace layout (ints); all vector bases 16B-aligned
    int*   counts   = (int*)d_ws;                         // NSCAN
    int*   offsets  = counts   + NSCAN;                   // NSCAN
    int*   partials = offsets  + NSCAN;                   // 64
    int*   rank     = partials + 64;                      // n_edges
    int*   edge_src = rank     + n_edges;                 // n_edges + 7*NSCAN + 64
    uint4* hsb      = (uint4*)(edge_src + n_edges + 7 * NSCAN + 64);  // (N+1)*8 uint4
    uint4* meanh    = hsb + (size_t)(N_NODES_C + 1) * 8;  // N*8 uint4

    // zero the histogram (ws is poisoned; everything else is fully rewritten)
    hipMemsetAsync(counts, 0, NSCAN * sizeof(int), stream);

    int n8 = n_feat / 8;   // 800000
    convert_fp16<<<(n8 + 8 + 255) / 256, 256, 0, stream>>>(h_src, hsb, n8);

    int nbE4 = ((n_edges + 3) / 4 + 255) / 256;
    edge_hist<<<nbE4, 256, 0, stream>>>(dst, counts, rank, n_edges);
    scan_block<<<NB_SCAN, SCAN_BS, 0, stream>>>(counts, offsets, partials);
    scan_add<<<NB_SCAN, SCAN_BS, 0, stream>>>(offsets, partials, counts, edge_src);
    edge_fill<<<nbE4, 256, 0, stream>>>(src, dst, rank, offsets, edge_src, n_edges);

    // one wave per node: 100000 waves = 25000 blocks of 256
    sage_gather<<<N_NODES_C / 4, 256, 0, stream>>>(
        hsb, offsets, counts, edge_src, meanh, N_NODES_C);

    sage_gemm<<<(N_NODES_C + 63) / 64, 256, 0, stream>>>(
        h_dst, meanh, weight, bias, out, N_NODES_C);
}

// Round 14
// 159.226 us; speedup vs baseline: 1.4241x; 1.4241x over previous
//
#include <hip/hip_runtime.h>
#include <hip/hip_bf16.h>
#include <hip/hip_fp16.h>

#define N_NODES_C 100000
#define NSCAN     102400      // N padded to 25 * 4096 for the scan
#define SCAN_BS   1024        // threads per scan block (4 elems each -> 4096/block)
#define NB_SCAN   (NSCAN / (SCAN_BS * 4))   // 25 blocks

// ---------------------------------------------------------------------------
// fp16 helpers: h_src stored as packed fp16 (uint = 2 halves)
// ---------------------------------------------------------------------------
union U2H { unsigned u; __half2 h; };

__device__ __forceinline__ __half2 addp(__half2 a, unsigned u)
{
    U2H c; c.u = u;
    return __hadd2(a, c.h);
}

__device__ __forceinline__ __half2 shfl_xor_h2(__half2 v, int m)
{
    U2H c; c.h = v;
    c.u = (unsigned)__shfl_xor((int)c.u, m, 64);
    return c.h;
}

// h_src f32 -> packed fp16 copy; row N_NODES_C is written as zeros (pad row)
__global__ __launch_bounds__(256) void convert_fp16(
    const float* __restrict__ x, uint4* __restrict__ y, int n8)
{
    int i = blockIdx.x * 256 + threadIdx.x;
    if (i >= n8 + 8) return;
    if (i >= n8) { y[i] = make_uint4(0u, 0u, 0u, 0u); return; }
    const float4* x4 = reinterpret_cast<const float4*>(x);
    float4 a = x4[i * 2 + 0];
    float4 b = x4[i * 2 + 1];
    U2H c0, c1, c2, c3;
    c0.h = __floats2half2_rn(a.x, a.y);
    c1.h = __floats2half2_rn(a.z, a.w);
    c2.h = __floats2half2_rn(b.x, b.y);
    c3.h = __floats2half2_rn(b.z, b.w);
    uint4 o;
    o.x = c0.u; o.y = c1.u; o.z = c2.u; o.w = c3.u;
    y[i] = o;
}

// ---------------------------------------------------------------------------
// CSR build (padded-to-8 segments):
// histogram(+rank) -> block scan of PADDED counts -> scan_add (+pad fill) -> fill
// ---------------------------------------------------------------------------
__global__ __launch_bounds__(256) void edge_hist(
    const int* __restrict__ dst, int* __restrict__ counts,
    int* __restrict__ rank, int n_edges)
{
    int i = blockIdx.x * 256 + threadIdx.x;
    int b4 = i * 4;
    if (b4 + 3 < n_edges) {
        int4 d = reinterpret_cast<const int4*>(dst)[i];
        int4 rk;
        rk.x = atomicAdd(&counts[d.x], 1);
        rk.y = atomicAdd(&counts[d.y], 1);
        rk.z = atomicAdd(&counts[d.z], 1);
        rk.w = atomicAdd(&counts[d.w], 1);
        reinterpret_cast<int4*>(rank)[i] = rk;
    } else {
        for (int e = b4; e < n_edges; ++e)
            rank[e] = atomicAdd(&counts[dst[e]], 1);
    }
}

__global__ __launch_bounds__(SCAN_BS) void scan_block(
    const int* __restrict__ counts, int* __restrict__ offsets,
    int* __restrict__ partials)
{
    __shared__ int sd[2][SCAN_BS];
    int t = threadIdx.x, b = blockIdx.x;
    int4 c = reinterpret_cast<const int4*>(counts)[b * SCAN_BS + t];
    int q0 = (c.x + 7) & ~7;
    int q1 = (c.y + 7) & ~7;
    int q2 = (c.z + 7) & ~7;
    int q3 = (c.w + 7) & ~7;
    int tot = q0 + q1 + q2 + q3;
    sd[0][t] = tot;
    __syncthreads();
    int pin = 0;
    #pragma unroll
    for (int off = 1; off < SCAN_BS; off <<= 1) {
        int v = sd[pin][t];
        if (t >= off) v += sd[pin][t - off];
        sd[pin ^ 1][t] = v;
        pin ^= 1;
        __syncthreads();
    }
    int incl = sd[pin][t];      // inclusive scan of per-thread padded sums
    int excl = incl - tot;
    int4 o;
    o.x = excl;
    o.y = excl + q0;
    o.z = excl + q0 + q1;
    o.w = excl + q0 + q1 + q2;
    reinterpret_cast<int4*>(offsets)[b * SCAN_BS + t] = o;
    if (t == SCAN_BS - 1) partials[b] = incl;
}

// add block bases; also fill each node's pad slots with the dummy index N
__global__ __launch_bounds__(SCAN_BS) void scan_add(
    int* __restrict__ offsets, const int* __restrict__ partials,
    const int* __restrict__ counts, int* __restrict__ edge_src)
{
    __shared__ int base_s;
    int b = blockIdx.x;
    if (threadIdx.x == 0) {
        int s = 0;
        for (int i = 0; i < b; ++i) s += partials[i];
        base_s = s;
    }
    __syncthreads();
    int i = b * SCAN_BS + threadIdx.x;
    int4 v = reinterpret_cast<int4*>(offsets)[i];
    v.x += base_s; v.y += base_s; v.z += base_s; v.w += base_s;
    reinterpret_cast<int4*>(offsets)[i] = v;
    int4 c = reinterpret_cast<const int4*>(counts)[i];
    int s, ep;
    s = v.x + c.x; ep = v.x + ((c.x + 7) & ~7); for (; s < ep; ++s) edge_src[s] = N_NODES_C;
    s = v.y + c.y; ep = v.y + ((c.y + 7) & ~7); for (; s < ep; ++s) edge_src[s] = N_NODES_C;
    s = v.z + c.z; ep = v.z + ((c.z + 7) & ~7); for (; s < ep; ++s) edge_src[s] = N_NODES_C;
    s = v.w + c.w; ep = v.w + ((c.w + 7) & ~7); for (; s < ep; ++s) edge_src[s] = N_NODES_C;
}

__global__ __launch_bounds__(256) void edge_fill(
    const int* __restrict__ src, const int* __restrict__ dst,
    const int* __restrict__ rank, const int* __restrict__ offsets,
    int* __restrict__ edge_src, int n_edges)
{
    int i = blockIdx.x * 256 + threadIdx.x;
    int b4 = i * 4;
    if (b4 + 3 < n_edges) {
        int4 s  = reinterpret_cast<const int4*>(src)[i];
        int4 d  = reinterpret_cast<const int4*>(dst)[i];
        int4 rk = reinterpret_cast<const int4*>(rank)[i];
        edge_src[offsets[d.x] + rk.x] = s.x;
        edge_src[offsets[d.y] + rk.y] = s.y;
        edge_src[offsets[d.z] + rk.z] = s.z;
        edge_src[offsets[d.w] + rk.w] = s.w;
    } else {
        for (int e = b4; e < n_edges; ++e)
            edge_src[offsets[dst[e]] + rank[e]] = src[e];
    }
}

// ---------------------------------------------------------------------------
// Gather: ONE WAVE PER NODE (100K waves -> TLP hides all gather latency).
// Confirmed fast in R13 (not in top-5 dispatches; phase sum ~20 us).
// ---------------------------------------------------------------------------
__global__ __launch_bounds__(256) void sage_gather(
    const uint4* __restrict__ hsb,      // packed fp16 h_src [(N+1)][8] uint4
    const int*   __restrict__ offsets,  // padded CSR offsets
    const int*   __restrict__ counts,   // raw degrees
    const int*   __restrict__ edge_src, // padded edge lists
    uint4*       __restrict__ meanh,    // out: fp16 mean rows [N][8] uint4
    int n_nodes)
{
    int wid  = (blockIdx.x * 256 + threadIdx.x) >> 6;   // node id (grid exact)
    int lane = threadIdx.x & 63;
    int slot = lane >> 3;
    int chunk = lane & 7;

    int e0  = offsets[wid];    // wave-uniform -> scalar loads
    int deg = counts[wid];
    int nit = (deg + 7) >> 3;

    __half2 a0, a1, a2, a3;
    {
        U2H z; z.u = 0u;
        a0 = z.h; a1 = z.h; a2 = z.h; a3 = z.h;
    }

    for (int it = 0; it < nit; ++it) {
        int s = edge_src[e0 + (it << 3) + slot];
        uint4 v = hsb[(size_t)s * 8 + chunk];
        a0 = addp(a0, v.x);
        a1 = addp(a1, v.y);
        a2 = addp(a2, v.z);
        a3 = addp(a3, v.w);
    }

    // reduce over the 8 slots (lane bits 3,4,5)
    #pragma unroll
    for (int m = 8; m < 64; m <<= 1) {
        a0 = __hadd2(a0, shfl_xor_h2(a0, m));
        a1 = __hadd2(a1, shfl_xor_h2(a1, m));
        a2 = __hadd2(a2, shfl_xor_h2(a2, m));
        a3 = __hadd2(a3, shfl_xor_h2(a3, m));
    }

    if (lane < 8) {
        float invd = 1.0f / (float)(deg > 1 ? deg : 1);
        U2H o0, o1, o2, o3;
        o0.h = __floats2half2_rn(__low2float(a0) * invd, __high2float(a0) * invd);
        o1.h = __floats2half2_rn(__low2float(a1) * invd, __high2float(a1) * invd);
        o2.h = __floats2half2_rn(__low2float(a2) * invd, __high2float(a2) * invd);
        o3.h = __floats2half2_rn(__low2float(a3) * invd, __high2float(a3) * invd);
        meanh[(size_t)wid * 8 + lane] = make_uint4(o0.u, o1.u, o2.u, o3.u);
    }
}

// ---------------------------------------------------------------------------
// GEMM epilogue: 64 nodes/block. BOTH X and W staged in LDS (32KB + 32KB,
// swizzled float4) -- R14 fix: R3..R13 streamed W from global per-thread
// (128 lane-divergent 16B loads/thread through the TA pipe) which made this
// kernel latency-bound at 128 us (HBM 4%, VALU 17%, Mfma 0). R2's W-in-LDS
// shape was the fast variant all along.
// ---------------------------------------------------------------------------
__global__ __launch_bounds__(256) void sage_gemm(
    const float* __restrict__ h_dst,
    const uint4* __restrict__ meanh,    // fp16 mean rows [N][8] uint4
    const float* __restrict__ weight,   // [64][128] row-major
    const float* __restrict__ bias,     // [64]
    float*       __restrict__ out,      // [N][64]
    int n_nodes)
{
    __shared__ float4 x4[64 * 32];   // x4[r][c] at r*32 + ((c + r) & 31)
    __shared__ float4 w4[64 * 32];   // w4[o][k4] at o*32 + ((k4 + (o>>2)) & 31)

    const int t    = threadIdx.x;
    const int base = blockIdx.x * 64;

    // stage W (once per block), swizzled: 8 float4 per thread
    #pragma unroll
    for (int q = 0; q < 8; ++q) {
        int idx = t + q * 256;        // 0..2047
        int o   = idx >> 5;
        int k4  = idx & 31;
        float4 wv = reinterpret_cast<const float4*>(weight)[o * 32 + k4];
        w4[o * 32 + ((k4 + (o >> 2)) & 31)] = wv;
    }

    // stage h_dst (cols 0..15): 4 float4 per thread
    #pragma unroll
    for (int q = 0; q < 4; ++q) {
        int idx = t + q * 256;        // 0..1023
        int r   = idx >> 4;
        int k4  = idx & 15;
        int g   = base + r;
        float4 xv = make_float4(0.f, 0.f, 0.f, 0.f);
        if (g < n_nodes)
            xv = reinterpret_cast<const float4*>(h_dst)[(size_t)g * 16 + k4];
        x4[r * 32 + ((k4 + r) & 31)] = xv;
    }

    // stage mean (cols 16..31): 2 uint4 per thread, unpack fp16 -> f32
    #pragma unroll
    for (int q = 0; q < 2; ++q) {
        int idx = t + q * 256;        // 0..511
        int r   = idx >> 3;
        int c8  = idx & 7;
        int g   = base + r;
        uint4 mv = make_uint4(0u, 0u, 0u, 0u);
        if (g < n_nodes)
            mv = meanh[(size_t)g * 8 + c8];
        U2H u0, u1, u2, u3;
        u0.u = mv.x; u1.u = mv.y; u2.u = mv.z; u3.u = mv.w;
        float4 lo = make_float4(__low2float(u0.h), __high2float(u0.h),
                                __low2float(u1.h), __high2float(u1.h));
        float4 hi = make_float4(__low2float(u2.h), __high2float(u2.h),
                                __low2float(u3.h), __high2float(u3.h));
        x4[r * 32 + (((16 + 2 * c8) + r) & 31)] = lo;
        x4[r * 32 + (((17 + 2 * c8) + r) & 31)] = hi;
    }
    __syncthreads();

    // GEMM: thread tile = 4 nodes x 4 outs; W from LDS (broadcast per m-group)
    const int m  = t & 15;    // out-group: o0 = 4m
    const int r0 = t >> 4;    // node base: rows r0 + 16*i
    const int o0 = m * 4;

    float4 bv = reinterpret_cast<const float4*>(bias)[m];

    float acc[4][4];
    #pragma unroll
    for (int i = 0; i < 4; ++i) {
        acc[i][0] = bv.x; acc[i][1] = bv.y; acc[i][2] = bv.z; acc[i][3] = bv.w;
    }

    #pragma unroll 4
    for (int k4 = 0; k4 < 32; ++k4) {
        float4 wv[4];
        #pragma unroll
        for (int jj = 0; jj < 4; ++jj) {
            int o = o0 + jj;                      // (o>>2) == m for all jj
            wv[jj] = w4[o * 32 + ((k4 + m) & 31)];
        }
        #pragma unroll
        for (int i = 0; i < 4; ++i) {
            int r = r0 + 16 * i;
            float4 xv = x4[r * 32 + ((k4 + r) & 31)];
            #pragma unroll
            for (int jj = 0; jj < 4; ++jj) {
                acc[i][jj] += xv.x * wv[jj].x + xv.y * wv[jj].y
                            + xv.z * wv[jj].z + xv.w * wv[jj].w;
            }
        }
    }

    #pragma unroll
    for (int i = 0; i < 4; ++i) {
        int g = base + r0 + 16 * i;
        if (g < n_nodes) {
            float4 ov = make_float4(acc[i][0], acc[i][1], acc[i][2], acc[i][3]);
            reinterpret_cast<float4*>(out)[(size_t)g * 16 + m] = ov;
        }
    }
}

// ---------------------------------------------------------------------------
extern "C" void kernel_launch(void* const* d_in, const int* in_sizes, int n_in,
                              void* d_out, int out_size, void* d_ws, size_t ws_size,
                              hipStream_t stream)
{
    const float* h_src  = (const float*)d_in[0];
    const float* h_dst  = (const float*)d_in[1];
    const int*   src    = (const int*)d_in[2];
    const int*   dst    = (const int*)d_in[3];
    const float* weight = (const float*)d_in[4];
    const float* bias   = (const float*)d_in[5];
    float*       out    = (float*)d_out;

    const int n_edges = in_sizes[2];
    const int n_feat  = in_sizes[0];   // N*64 floats

    // workspace layout (ints); all vector bases 16B-aligned
    int*   counts   = (int*)d_ws;                         // NSCAN
    int*   offsets  = counts   + NSCAN;                   // NSCAN
    int*   partials = offsets  + NSCAN;                   // 64
    int*   rank     = partials + 64;                      // n_edges
    int*   edge_src = rank     + n_edges;                 // n_edges + 7*NSCAN + 64
    uint4* hsb      = (uint4*)(edge_src + n_edges + 7 * NSCAN + 64);  // (N+1)*8 uint4
    uint4* meanh    = hsb + (size_t)(N_NODES_C + 1) * 8;  // N*8 uint4

    // zero the histogram (ws is poisoned; everything else is fully rewritten)
    hipMemsetAsync(counts, 0, NSCAN * sizeof(int), stream);

    int n8 = n_feat / 8;   // 800000
    convert_fp16<<<(n8 + 8 + 255) / 256, 256, 0, stream>>>(h_src, hsb, n8);

    int nbE4 = ((n_edges + 3) / 4 + 255) / 256;
    edge_hist<<<nbE4, 256, 0, stream>>>(dst, counts, rank, n_edges);
    scan_block<<<NB_SCAN, SCAN_BS, 0, stream>>>(counts, offsets, partials);
    scan_add<<<NB_SCAN, SCAN_BS, 0, stream>>>(offsets, partials, counts, edge_src);
    edge_fill<<<nbE4, 256, 0, stream>>>(src, dst, rank, offsets, edge_src, n_edges);

    // one wave per node: 100000 waves = 25000 blocks of 256
    sage_gather<<<N_NODES_C / 4, 256, 0, stream>>>(
        hsb, offsets, counts, edge_src, meanh, N_NODES_C);

    sage_gemm<<<(N_NODES_C + 63) / 64, 256, 0, stream>>>(
        h_dst, meanh, weight, bias, out, N_NODES_C);
}

// Round 16
// 144.047 us; speedup vs baseline: 1.5742x; 1.1054x over previous
//
#include <hip/hip_runtime.h>
#include <hip/hip_bf16.h>
#include <hip/hip_fp16.h>

#define N_NODES_C 100000
#define NSCAN     102400      // N padded to 25 * 4096 for the scan
#define SCAN_BS   1024        // threads per scan block (4 elems each -> 4096/block)
#define NB_SCAN   (NSCAN / (SCAN_BS * 4))   // 25 blocks

// ---------------------------------------------------------------------------
// fp16 helpers: h_src stored as packed fp16 (uint = 2 halves)
// ---------------------------------------------------------------------------
union U2H { unsigned u; __half2 h; };

typedef _Float16 h2v __attribute__((ext_vector_type(2)));   // for fdot2
typedef __fp16   p2v __attribute__((ext_vector_type(2)));   // cvt_pkrtz result
union U2HV { unsigned u; h2v h; };
union U2PV { unsigned u; p2v p; };

__device__ __forceinline__ __half2 addp(__half2 a, unsigned u)
{
    U2H c; c.u = u;
    return __hadd2(a, c.h);
}

__device__ __forceinline__ __half2 shfl_xor_h2(__half2 v, int m)
{
    U2H c; c.h = v;
    c.u = (unsigned)__shfl_xor((int)c.u, m, 64);
    return c.h;
}

// 2-way fp16 dot with f32 accumulator (v_dot2_f32_f16)
__device__ __forceinline__ float dot2(unsigned xu, unsigned wu, float c)
{
#if __has_builtin(__builtin_amdgcn_fdot2)
    U2HV a, b;
    a.u = xu; b.u = wu;
    return __builtin_amdgcn_fdot2(a.h, b.h, c, false);
#else
    asm("v_dot2_f32_f16 %0, %1, %2, %0" : "+v"(c) : "v"(xu), "v"(wu));
    return c;
#endif
}

// pack two float4 -> uint4 of 8 fp16 (rtz)
__device__ __forceinline__ uint4 pk8(float4 f0, float4 f1)
{
    U2PV a, b, c, d;
    a.p = __builtin_amdgcn_cvt_pkrtz(f0.x, f0.y);
    b.p = __builtin_amdgcn_cvt_pkrtz(f0.z, f0.w);
    c.p = __builtin_amdgcn_cvt_pkrtz(f1.x, f1.y);
    d.p = __builtin_amdgcn_cvt_pkrtz(f1.z, f1.w);
    return make_uint4(a.u, b.u, c.u, d.u);
}

// h_src f32 -> packed fp16 copy; row N_NODES_C is written as zeros (pad row)
__global__ __launch_bounds__(256) void convert_fp16(
    const float* __restrict__ x, uint4* __restrict__ y, int n8)
{
    int i = blockIdx.x * 256 + threadIdx.x;
    if (i >= n8 + 8) return;
    if (i >= n8) { y[i] = make_uint4(0u, 0u, 0u, 0u); return; }
    const float4* x4 = reinterpret_cast<const float4*>(x);
    float4 a = x4[i * 2 + 0];
    float4 b = x4[i * 2 + 1];
    U2H c0, c1, c2, c3;
    c0.h = __floats2half2_rn(a.x, a.y);
    c1.h = __floats2half2_rn(a.z, a.w);
    c2.h = __floats2half2_rn(b.x, b.y);
    c3.h = __floats2half2_rn(b.z, b.w);
    uint4 o;
    o.x = c0.u; o.y = c1.u; o.z = c2.u; o.w = c3.u;
    y[i] = o;
}

// ---------------------------------------------------------------------------
// CSR build (padded-to-8 segments):
// histogram(+rank) -> block scan of PADDED counts -> scan_add (+pad fill) -> fill
// ---------------------------------------------------------------------------
__global__ __launch_bounds__(256) void edge_hist(
    const int* __restrict__ dst, int* __restrict__ counts,
    int* __restrict__ rank, int n_edges)
{
    int i = blockIdx.x * 256 + threadIdx.x;
    int b4 = i * 4;
    if (b4 + 3 < n_edges) {
        int4 d = reinterpret_cast<const int4*>(dst)[i];
        int4 rk;
        rk.x = atomicAdd(&counts[d.x], 1);
        rk.y = atomicAdd(&counts[d.y], 1);
        rk.z = atomicAdd(&counts[d.z], 1);
        rk.w = atomicAdd(&counts[d.w], 1);
        reinterpret_cast<int4*>(rank)[i] = rk;
    } else {
        for (int e = b4; e < n_edges; ++e)
            rank[e] = atomicAdd(&counts[dst[e]], 1);
    }
}

__global__ __launch_bounds__(SCAN_BS) void scan_block(
    const int* __restrict__ counts, int* __restrict__ offsets,
    int* __restrict__ partials)
{
    __shared__ int sd[2][SCAN_BS];
    int t = threadIdx.x, b = blockIdx.x;
    int4 c = reinterpret_cast<const int4*>(counts)[b * SCAN_BS + t];
    int q0 = (c.x + 7) & ~7;
    int q1 = (c.y + 7) & ~7;
    int q2 = (c.z + 7) & ~7;
    int q3 = (c.w + 7) & ~7;
    int tot = q0 + q1 + q2 + q3;
    sd[0][t] = tot;
    __syncthreads();
    int pin = 0;
    #pragma unroll
    for (int off = 1; off < SCAN_BS; off <<= 1) {
        int v = sd[pin][t];
        if (t >= off) v += sd[pin][t - off];
        sd[pin ^ 1][t] = v;
        pin ^= 1;
        __syncthreads();
    }
    int incl = sd[pin][t];      // inclusive scan of per-thread padded sums
    int excl = incl - tot;
    int4 o;
    o.x = excl;
    o.y = excl + q0;
    o.z = excl + q0 + q1;
    o.w = excl + q0 + q1 + q2;
    reinterpret_cast<int4*>(offsets)[b * SCAN_BS + t] = o;
    if (t == SCAN_BS - 1) partials[b] = incl;
}

// add block bases; also fill each node's pad slots with the dummy index N
__global__ __launch_bounds__(SCAN_BS) void scan_add(
    int* __restrict__ offsets, const int* __restrict__ partials,
    const int* __restrict__ counts, int* __restrict__ edge_src)
{
    __shared__ int base_s;
    int b = blockIdx.x;
    if (threadIdx.x == 0) {
        int s = 0;
        for (int i = 0; i < b; ++i) s += partials[i];
        base_s = s;
    }
    __syncthreads();
    int i = b * SCAN_BS + threadIdx.x;
    int4 v = reinterpret_cast<int4*>(offsets)[i];
    v.x += base_s; v.y += base_s; v.z += base_s; v.w += base_s;
    reinterpret_cast<int4*>(offsets)[i] = v;
    int4 c = reinterpret_cast<const int4*>(counts)[i];
    int s, ep;
    s = v.x + c.x; ep = v.x + ((c.x + 7) & ~7); for (; s < ep; ++s) edge_src[s] = N_NODES_C;
    s = v.y + c.y; ep = v.y + ((c.y + 7) & ~7); for (; s < ep; ++s) edge_src[s] = N_NODES_C;
    s = v.z + c.z; ep = v.z + ((c.z + 7) & ~7); for (; s < ep; ++s) edge_src[s] = N_NODES_C;
    s = v.w + c.w; ep = v.w + ((c.w + 7) & ~7); for (; s < ep; ++s) edge_src[s] = N_NODES_C;
}

__global__ __launch_bounds__(256) void edge_fill(
    const int* __restrict__ src, const int* __restrict__ dst,
    const int* __restrict__ rank, const int* __restrict__ offsets,
    int* __restrict__ edge_src, int n_edges)
{
    int i = blockIdx.x * 256 + threadIdx.x;
    int b4 = i * 4;
    if (b4 + 3 < n_edges) {
        int4 s  = reinterpret_cast<const int4*>(src)[i];
        int4 d  = reinterpret_cast<const int4*>(dst)[i];
        int4 rk = reinterpret_cast<const int4*>(rank)[i];
        edge_src[offsets[d.x] + rk.x] = s.x;
        edge_src[offsets[d.y] + rk.y] = s.y;
        edge_src[offsets[d.z] + rk.z] = s.z;
        edge_src[offsets[d.w] + rk.w] = s.w;
    } else {
        for (int e = b4; e < n_edges; ++e)
            edge_src[offsets[dst[e]] + rank[e]] = src[e];
    }
}

// ---------------------------------------------------------------------------
// Gather: ONE WAVE PER NODE (100K waves -> TLP hides all gather latency).
// Confirmed fast in R13/R14 (below top-5 cutoff).
// ---------------------------------------------------------------------------
__global__ __launch_bounds__(256) void sage_gather(
    const uint4* __restrict__ hsb,      // packed fp16 h_src [(N+1)][8] uint4
    const int*   __restrict__ offsets,  // padded CSR offsets
    const int*   __restrict__ counts,   // raw degrees
    const int*   __restrict__ edge_src, // padded edge lists
    uint4*       __restrict__ meanh,    // out: fp16 mean rows [N][8] uint4
    int n_nodes)
{
    int wid  = (blockIdx.x * 256 + threadIdx.x) >> 6;   // node id (grid exact)
    int lane = threadIdx.x & 63;
    int slot = lane >> 3;
    int chunk = lane & 7;

    int e0  = offsets[wid];    // wave-uniform -> scalar loads
    int deg = counts[wid];
    int nit = (deg + 7) >> 3;

    __half2 a0, a1, a2, a3;
    {
        U2H z; z.u = 0u;
        a0 = z.h; a1 = z.h; a2 = z.h; a3 = z.h;
    }

    for (int it = 0; it < nit; ++it) {
        int s = edge_src[e0 + (it << 3) + slot];
        uint4 v = hsb[(size_t)s * 8 + chunk];
        a0 = addp(a0, v.x);
        a1 = addp(a1, v.y);
        a2 = addp(a2, v.z);
        a3 = addp(a3, v.w);
    }

    // reduce over the 8 slots (lane bits 3,4,5)
    #pragma unroll
    for (int m = 8; m < 64; m <<= 1) {
        a0 = __hadd2(a0, shfl_xor_h2(a0, m));
        a1 = __hadd2(a1, shfl_xor_h2(a1, m));
        a2 = __hadd2(a2, shfl_xor_h2(a2, m));
        a3 = __hadd2(a3, shfl_xor_h2(a3, m));
    }

    if (lane < 8) {
        float invd = 1.0f / (float)(deg > 1 ? deg : 1);
        U2H o0, o1, o2, o3;
        o0.h = __floats2half2_rn(__low2float(a0) * invd, __high2float(a0) * invd);
        o1.h = __floats2half2_rn(__low2float(a1) * invd, __high2float(a1) * invd);
        o2.h = __floats2half2_rn(__low2float(a2) * invd, __high2float(a2) * invd);
        o3.h = __floats2half2_rn(__low2float(a3) * invd, __high2float(a3) * invd);
        meanh[(size_t)wid * 8 + lane] = make_uint4(o0.u, o1.u, o2.u, o3.u);
    }
}

// ---------------------------------------------------------------------------
// GEMM epilogue v2: X and W both packed fp16 in LDS (16KB + 16KB = 32KB),
// inner loop uses v_dot2_f32_f16 -> half the ds_reads and half the VALU
// instructions vs the f32 version (which ran 47.5us at 2 blocks/CU).
// Row = 128 halves = 16 uint4; swizzled ((c4 + r) & 15) / ((c4 + (o>>2)) & 15).
// ---------------------------------------------------------------------------
__global__ __launch_bounds__(256) void sage_gemm(
    const float* __restrict__ h_dst,
    const uint4* __restrict__ meanh,    // fp16 mean rows [N][8] uint4
    const float* __restrict__ weight,   // [64][128] row-major
    const float* __restrict__ bias,     // [64]
    float*       __restrict__ out,      // [N][64]
    int n_nodes)
{
    __shared__ uint4 xh4[64 * 16];   // x row r: 16 uint4, col c4 at r*16+((c4+r)&15)
    __shared__ uint4 wh4[64 * 16];   // w row o: 16 uint4, col c4 at o*16+((c4+(o>>2))&15)

    const int t    = threadIdx.x;
    const int base = blockIdx.x * 64;

    const float4* w4g = reinterpret_cast<const float4*>(weight);
    const float4* hd4 = reinterpret_cast<const float4*>(h_dst);

    // stage W as fp16 (once per block): 4 uint4 per thread
    #pragma unroll
    for (int q = 0; q < 4; ++q) {
        int idx = t + q * 256;        // 0..1023
        int o   = idx >> 4;
        int c4  = idx & 15;
        float4 f0 = w4g[o * 32 + c4 * 2 + 0];
        float4 f1 = w4g[o * 32 + c4 * 2 + 1];
        wh4[o * 16 + ((c4 + (o >> 2)) & 15)] = pk8(f0, f1);
    }

    // stage h_dst (c4 = 0..7) as fp16: 2 uint4 per thread
    #pragma unroll
    for (int q = 0; q < 2; ++q) {
        int idx = t + q * 256;        // 0..511
        int r   = idx >> 3;
        int c4  = idx & 7;
        int g   = base + r;
        float4 f0 = make_float4(0.f, 0.f, 0.f, 0.f);
        float4 f1 = f0;
        if (g < n_nodes) {
            f0 = hd4[(size_t)g * 16 + c4 * 2 + 0];
            f1 = hd4[(size_t)g * 16 + c4 * 2 + 1];
        }
        xh4[r * 16 + ((c4 + r) & 15)] = pk8(f0, f1);
    }

    // stage mean (c4 = 8..15), already fp16: 2 uint4 per thread
    #pragma unroll
    for (int q = 0; q < 2; ++q) {
        int idx = t + q * 256;        // 0..511
        int r   = idx >> 3;
        int c8  = idx & 7;
        int g   = base + r;
        uint4 mv = make_uint4(0u, 0u, 0u, 0u);
        if (g < n_nodes)
            mv = meanh[(size_t)g * 8 + c8];
        xh4[r * 16 + (((8 + c8) + r) & 15)] = mv;
    }
    __syncthreads();

    // GEMM: thread tile = 4 nodes x 4 outs, v_dot2_f32_f16 inner loop
    const int m  = t & 15;    // out-group: o0 = 4m
    const int r0 = t >> 4;    // node base: rows r0 + 16*i
    const int o0 = m * 4;

    float4 bv = reinterpret_cast<const float4*>(bias)[m];

    float acc[4][4];
    #pragma unroll
    for (int i = 0; i < 4; ++i) {
        acc[i][0] = bv.x; acc[i][1] = bv.y; acc[i][2] = bv.z; acc[i][3] = bv.w;
    }

    #pragma unroll 4
    for (int c4 = 0; c4 < 16; ++c4) {
        uint4 wq[4];
        #pragma unroll
        for (int jj = 0; jj < 4; ++jj) {
            int o = o0 + jj;                      // (o>>2) == m for all jj
            wq[jj] = wh4[o * 16 + ((c4 + m) & 15)];
        }
        #pragma unroll
        for (int i = 0; i < 4; ++i) {
            int r = r0 + 16 * i;
            uint4 xq = xh4[r * 16 + ((c4 + r) & 15)];
            #pragma unroll
            for (int jj = 0; jj < 4; ++jj) {
                float a = acc[i][jj];
                a = dot2(xq.x, wq[jj].x, a);
                a = dot2(xq.y, wq[jj].y, a);
                a = dot2(xq.z, wq[jj].z, a);
                a = dot2(xq.w, wq[jj].w, a);
                acc[i][jj] = a;
            }
        }
    }

    #pragma unroll
    for (int i = 0; i < 4; ++i) {
        int g = base + r0 + 16 * i;
        if (g < n_nodes) {
            float4 ov = make_float4(acc[i][0], acc[i][1], acc[i][2], acc[i][3]);
            reinterpret_cast<float4*>(out)[(size_t)g * 16 + m] = ov;
        }
    }
}

// ---------------------------------------------------------------------------
extern "C" void kernel_launch(void* const* d_in, const int* in_sizes, int n_in,
                              void* d_out, int out_size, void* d_ws, size_t ws_size,
                              hipStream_t stream)
{
    const float* h_src  = (const float*)d_in[0];
    const float* h_dst  = (const float*)d_in[1];
    const int*   src    = (const int*)d_in[2];
    const int*   dst    = (const int*)d_in[3];
    const float* weight = (const float*)d_in[4];
    const float* bias   = (const float*)d_in[5];
    float*       out    = (float*)d_out;

    const int n_edges = in_sizes[2];
    const int n_feat  = in_sizes[0];   // N*64 floats

    // workspace layout (ints); all vector bases 16B-aligned
    int*   counts   = (int*)d_ws;                         // NSCAN
    int*   offsets  = counts   + NSCAN;                   // NSCAN
    int*   partials = offsets  + NSCAN;                   // 64
    int*   rank     = partials + 64;                      // n_edges
    int*   edge_src = rank     + n_edges;                 // n_edges + 7*NSCAN + 64
    uint4* hsb      = (uint4*)(edge_src + n_edges + 7 * NSCAN + 64);  // (N+1)*8 uint4
    uint4* meanh    = hsb + (size_t)(N_NODES_C + 1) * 8;  // N*8 uint4

    // zero the histogram (ws is poisoned; everything else is fully rewritten)
    hipMemsetAsync(counts, 0, NSCAN * sizeof(int), stream);

    int n8 = n_feat / 8;   // 800000
    convert_fp16<<<(n8 + 8 + 255) / 256, 256, 0, stream>>>(h_src, hsb, n8);

    int nbE4 = ((n_edges + 3) / 4 + 255) / 256;
    edge_hist<<<nbE4, 256, 0, stream>>>(dst, counts, rank, n_edges);
    scan_block<<<NB_SCAN, SCAN_BS, 0, stream>>>(counts, offsets, partials);
    scan_add<<<NB_SCAN, SCAN_BS, 0, stream>>>(offsets, partials, counts, edge_src);
    edge_fill<<<nbE4, 256, 0, stream>>>(src, dst, rank, offsets, edge_src, n_edges);

    // one wave per node: 100000 waves = 25000 blocks of 256
    sage_gather<<<N_NODES_C / 4, 256, 0, stream>>>(
        hsb, offsets, counts, edge_src, meanh, N_NODES_C);

    sage_gemm<<<(N_NODES_C + 63) / 64, 256, 0, stream>>>(
        h_dst, meanh, weight, bias, out, N_NODES_C);
}

// Round 17
// 136.864 us; speedup vs baseline: 1.6568x; 1.0525x over previous
//
#include <hip/hip_runtime.h>
#include <hip/hip_bf16.h>
#include <hip/hip_fp16.h>

#define N_NODES_C 100000
#define NSCAN     102400      // N padded to 25 * 4096 for the scan
#define SCAN_BS   1024        // threads per scan block (4 elems each -> 4096/block)
#define NB_SCAN   (NSCAN / (SCAN_BS * 4))   // 25 blocks

// ---------------------------------------------------------------------------
// fp16 helpers: h_src stored as packed fp16 (uint = 2 halves)
// ---------------------------------------------------------------------------
union U2H { unsigned u; __half2 h; };

typedef _Float16 h2v __attribute__((ext_vector_type(2)));   // for fdot2
typedef __fp16   p2v __attribute__((ext_vector_type(2)));   // cvt_pkrtz result
union U2HV { unsigned u; h2v h; };
union U2PV { unsigned u; p2v p; };

__device__ __forceinline__ __half2 addp(__half2 a, unsigned u)
{
    U2H c; c.u = u;
    return __hadd2(a, c.h);
}

__device__ __forceinline__ __half2 shfl_xor_h2(__half2 v, int m)
{
    U2H c; c.h = v;
    c.u = (unsigned)__shfl_xor((int)c.u, m, 64);
    return c.h;
}

// 2-way fp16 dot with f32 accumulator (v_dot2_f32_f16)
__device__ __forceinline__ float dot2(unsigned xu, unsigned wu, float c)
{
#if __has_builtin(__builtin_amdgcn_fdot2)
    U2HV a, b;
    a.u = xu; b.u = wu;
    return __builtin_amdgcn_fdot2(a.h, b.h, c, false);
#else
    asm("v_dot2_f32_f16 %0, %1, %2, %0" : "+v"(c) : "v"(xu), "v"(wu));
    return c;
#endif
}

// pack two float4 -> uint4 of 8 fp16 (rtz)
__device__ __forceinline__ uint4 pk8(float4 f0, float4 f1)
{
    U2PV a, b, c, d;
    a.p = __builtin_amdgcn_cvt_pkrtz(f0.x, f0.y);
    b.p = __builtin_amdgcn_cvt_pkrtz(f0.z, f0.w);
    c.p = __builtin_amdgcn_cvt_pkrtz(f1.x, f1.y);
    d.p = __builtin_amdgcn_cvt_pkrtz(f1.z, f1.w);
    return make_uint4(a.u, b.u, c.u, d.u);
}

// h_src f32 -> packed fp16 copy; row N_NODES_C is written as zeros (pad row)
__global__ __launch_bounds__(256) void convert_fp16(
    const float* __restrict__ x, uint4* __restrict__ y, int n8)
{
    int i = blockIdx.x * 256 + threadIdx.x;
    if (i >= n8 + 8) return;
    if (i >= n8) { y[i] = make_uint4(0u, 0u, 0u, 0u); return; }
    const float4* x4 = reinterpret_cast<const float4*>(x);
    float4 a = x4[i * 2 + 0];
    float4 b = x4[i * 2 + 1];
    U2H c0, c1, c2, c3;
    c0.h = __floats2half2_rn(a.x, a.y);
    c1.h = __floats2half2_rn(a.z, a.w);
    c2.h = __floats2half2_rn(b.x, b.y);
    c3.h = __floats2half2_rn(b.z, b.w);
    uint4 o;
    o.x = c0.u; o.y = c1.u; o.z = c2.u; o.w = c3.u;
    y[i] = o;
}

// ---------------------------------------------------------------------------
// CSR build (unpadded): histogram(+rank) -> block scan -> scan_add -> fill
// Gather handles segment tails with a per-lane clamp, so no pad slots needed.
// ---------------------------------------------------------------------------
__global__ __launch_bounds__(256) void edge_hist(
    const int* __restrict__ dst, int* __restrict__ counts,
    int* __restrict__ rank, int n_edges)
{
    int i = blockIdx.x * 256 + threadIdx.x;
    int b2 = i * 2;
    if (b2 + 1 < n_edges) {
        int2 d = reinterpret_cast<const int2*>(dst)[i];
        int2 rk;
        rk.x = atomicAdd(&counts[d.x], 1);
        rk.y = atomicAdd(&counts[d.y], 1);
        reinterpret_cast<int2*>(rank)[i] = rk;
    } else {
        for (int e = b2; e < n_edges; ++e)
            rank[e] = atomicAdd(&counts[dst[e]], 1);
    }
}

__global__ __launch_bounds__(SCAN_BS) void scan_block(
    const int* __restrict__ counts, int* __restrict__ offsets,
    int* __restrict__ partials)
{
    __shared__ int sd[2][SCAN_BS];
    int t = threadIdx.x, b = blockIdx.x;
    int4 c = reinterpret_cast<const int4*>(counts)[b * SCAN_BS + t];
    int tot = c.x + c.y + c.z + c.w;
    sd[0][t] = tot;
    __syncthreads();
    int pin = 0;
    #pragma unroll
    for (int off = 1; off < SCAN_BS; off <<= 1) {
        int v = sd[pin][t];
        if (t >= off) v += sd[pin][t - off];
        sd[pin ^ 1][t] = v;
        pin ^= 1;
        __syncthreads();
    }
    int incl = sd[pin][t];      // inclusive scan of per-thread sums
    int excl = incl - tot;
    int4 o;
    o.x = excl;
    o.y = excl + c.x;
    o.z = excl + c.x + c.y;
    o.w = excl + c.x + c.y + c.z;
    reinterpret_cast<int4*>(offsets)[b * SCAN_BS + t] = o;
    if (t == SCAN_BS - 1) partials[b] = incl;
}

// add block bases
__global__ __launch_bounds__(SCAN_BS) void scan_add(
    int* __restrict__ offsets, const int* __restrict__ partials)
{
    __shared__ int base_s;
    int b = blockIdx.x;
    if (threadIdx.x == 0) {
        int s = 0;
        for (int i = 0; i < b; ++i) s += partials[i];
        base_s = s;
    }
    __syncthreads();
    int i = b * SCAN_BS + threadIdx.x;
    int4 v = reinterpret_cast<int4*>(offsets)[i];
    v.x += base_s; v.y += base_s; v.z += base_s; v.w += base_s;
    reinterpret_cast<int4*>(offsets)[i] = v;
}

__global__ __launch_bounds__(256) void edge_fill(
    const int* __restrict__ src, const int* __restrict__ dst,
    const int* __restrict__ rank, const int* __restrict__ offsets,
    int* __restrict__ edge_src, int n_edges)
{
    int i = blockIdx.x * 256 + threadIdx.x;
    int b2 = i * 2;
    if (b2 + 1 < n_edges) {
        int2 s  = reinterpret_cast<const int2*>(src)[i];
        int2 d  = reinterpret_cast<const int2*>(dst)[i];
        int2 rk = reinterpret_cast<const int2*>(rank)[i];
        edge_src[offsets[d.x] + rk.x] = s.x;
        edge_src[offsets[d.y] + rk.y] = s.y;
    } else {
        for (int e = b2; e < n_edges; ++e)
            edge_src[offsets[dst[e]] + rank[e]] = src[e];
    }
}

// ---------------------------------------------------------------------------
// Gather: ONE WAVE PER NODE (100K waves -> TLP hides all gather latency).
// Tail handled per-lane: idx >= e1 -> read the zero pad row (index N).
// ---------------------------------------------------------------------------
__global__ __launch_bounds__(256) void sage_gather(
    const uint4* __restrict__ hsb,      // packed fp16 h_src [(N+1)][8] uint4
    const int*   __restrict__ offsets,  // CSR offsets (offsets[N] = n_edges)
    const int*   __restrict__ edge_src, // edge lists
    uint4*       __restrict__ meanh,    // out: fp16 mean rows [N][8] uint4
    int n_nodes)
{
    int wid  = (blockIdx.x * 256 + threadIdx.x) >> 6;   // node id (grid exact)
    int lane = threadIdx.x & 63;
    int slot = lane >> 3;
    int chunk = lane & 7;

    int e0  = offsets[wid];
    int e1  = offsets[wid + 1];
    int deg = e1 - e0;
    int nit = (deg + 7) >> 3;

    __half2 a0, a1, a2, a3;
    {
        U2H z; z.u = 0u;
        a0 = z.h; a1 = z.h; a2 = z.h; a3 = z.h;
    }

    for (int it = 0; it < nit; ++it) {
        int idx = e0 + (it << 3) + slot;
        int s = (idx < e1) ? edge_src[idx] : N_NODES_C;   // zero row for tail
        uint4 v = hsb[(size_t)s * 8 + chunk];
        a0 = addp(a0, v.x);
        a1 = addp(a1, v.y);
        a2 = addp(a2, v.z);
        a3 = addp(a3, v.w);
    }

    // reduce over the 8 slots (lane bits 3,4,5)
    #pragma unroll
    for (int m = 8; m < 64; m <<= 1) {
        a0 = __hadd2(a0, shfl_xor_h2(a0, m));
        a1 = __hadd2(a1, shfl_xor_h2(a1, m));
        a2 = __hadd2(a2, shfl_xor_h2(a2, m));
        a3 = __hadd2(a3, shfl_xor_h2(a3, m));
    }

    if (lane < 8) {
        float invd = 1.0f / (float)(deg > 1 ? deg : 1);
        U2H o0, o1, o2, o3;
        o0.h = __floats2half2_rn(__low2float(a0) * invd, __high2float(a0) * invd);
        o1.h = __floats2half2_rn(__low2float(a1) * invd, __high2float(a1) * invd);
        o2.h = __floats2half2_rn(__low2float(a2) * invd, __high2float(a2) * invd);
        o3.h = __floats2half2_rn(__low2float(a3) * invd, __high2float(a3) * invd);
        meanh[(size_t)wid * 8 + lane] = make_uint4(o0.u, o1.u, o2.u, o3.u);
    }
}

// ---------------------------------------------------------------------------
// GEMM epilogue: X and W both packed fp16 in LDS (16KB + 16KB = 32KB),
// v_dot2_f32_f16 inner loop (halved ds_reads + VALU vs f32 version).
// ---------------------------------------------------------------------------
__global__ __launch_bounds__(256) void sage_gemm(
    const float* __restrict__ h_dst,
    const uint4* __restrict__ meanh,    // fp16 mean rows [N][8] uint4
    const float* __restrict__ weight,   // [64][128] row-major
    const float* __restrict__ bias,     // [64]
    float*       __restrict__ out,      // [N][64]
    int n_nodes)
{
    __shared__ uint4 xh4[64 * 16];   // x row r: 16 uint4, col c4 at r*16+((c4+r)&15)
    __shared__ uint4 wh4[64 * 16];   // w row o: 16 uint4, col c4 at o*16+((c4+(o>>2))&15)

    const int t    = threadIdx.x;
    const int base = blockIdx.x * 64;

    const float4* w4g = reinterpret_cast<const float4*>(weight);
    const float4* hd4 = reinterpret_cast<const float4*>(h_dst);

    // stage W as fp16 (once per block): 4 uint4 per thread
    #pragma unroll
    for (int q = 0; q < 4; ++q) {
        int idx = t + q * 256;        // 0..1023
        int o   = idx >> 4;
        int c4  = idx & 15;
        float4 f0 = w4g[o * 32 + c4 * 2 + 0];
        float4 f1 = w4g[o * 32 + c4 * 2 + 1];
        wh4[o * 16 + ((c4 + (o >> 2)) & 15)] = pk8(f0, f1);
    }

    // stage h_dst (c4 = 0..7) as fp16: 2 uint4 per thread
    #pragma unroll
    for (int q = 0; q < 2; ++q) {
        int idx = t + q * 256;        // 0..511
        int r   = idx >> 3;
        int c4  = idx & 7;
        int g   = base + r;
        float4 f0 = make_float4(0.f, 0.f, 0.f, 0.f);
        float4 f1 = f0;
        if (g < n_nodes) {
            f0 = hd4[(size_t)g * 16 + c4 * 2 + 0];
            f1 = hd4[(size_t)g * 16 + c4 * 2 + 1];
        }
        xh4[r * 16 + ((c4 + r) & 15)] = pk8(f0, f1);
    }

    // stage mean (c4 = 8..15), already fp16: 2 uint4 per thread
    #pragma unroll
    for (int q = 0; q < 2; ++q) {
        int idx = t + q * 256;        // 0..511
        int r   = idx >> 3;
        int c8  = idx & 7;
        int g   = base + r;
        uint4 mv = make_uint4(0u, 0u, 0u, 0u);
        if (g < n_nodes)
            mv = meanh[(size_t)g * 8 + c8];
        xh4[r * 16 + (((8 + c8) + r) & 15)] = mv;
    }
    __syncthreads();

    // GEMM: thread tile = 4 nodes x 4 outs, v_dot2_f32_f16 inner loop
    const int m  = t & 15;    // out-group: o0 = 4m
    const int r0 = t >> 4;    // node base: rows r0 + 16*i
    const int o0 = m * 4;

    float4 bv = reinterpret_cast<const float4*>(bias)[m];

    float acc[4][4];
    #pragma unroll
    for (int i = 0; i < 4; ++i) {
        acc[i][0] = bv.x; acc[i][1] = bv.y; acc[i][2] = bv.z; acc[i][3] = bv.w;
    }

    #pragma unroll 4
    for (int c4 = 0; c4 < 16; ++c4) {
        uint4 wq[4];
        #pragma unroll
        for (int jj = 0; jj < 4; ++jj) {
            int o = o0 + jj;                      // (o>>2) == m for all jj
            wq[jj] = wh4[o * 16 + ((c4 + m) & 15)];
        }
        #pragma unroll
        for (int i = 0; i < 4; ++i) {
            int r = r0 + 16 * i;
            uint4 xq = xh4[r * 16 + ((c4 + r) & 15)];
            #pragma unroll
            for (int jj = 0; jj < 4; ++jj) {
                float a = acc[i][jj];
                a = dot2(xq.x, wq[jj].x, a);
                a = dot2(xq.y, wq[jj].y, a);
                a = dot2(xq.z, wq[jj].z, a);
                a = dot2(xq.w, wq[jj].w, a);
                acc[i][jj] = a;
            }
        }
    }

    #pragma unroll
    for (int i = 0; i < 4; ++i) {
        int g = base + r0 + 16 * i;
        if (g < n_nodes) {
            float4 ov = make_float4(acc[i][0], acc[i][1], acc[i][2], acc[i][3]);
            reinterpret_cast<float4*>(out)[(size_t)g * 16 + m] = ov;
        }
    }
}

// ---------------------------------------------------------------------------
extern "C" void kernel_launch(void* const* d_in, const int* in_sizes, int n_in,
                              void* d_out, int out_size, void* d_ws, size_t ws_size,
                              hipStream_t stream)
{
    const float* h_src  = (const float*)d_in[0];
    const float* h_dst  = (const float*)d_in[1];
    const int*   src    = (const int*)d_in[2];
    const int*   dst    = (const int*)d_in[3];
    const float* weight = (const float*)d_in[4];
    const float* bias   = (const float*)d_in[5];
    float*       out    = (float*)d_out;

    const int n_edges = in_sizes[2];
    const int n_feat  = in_sizes[0];   // N*64 floats

    // workspace layout (ints); all vector bases 16B-aligned
    int*   counts   = (int*)d_ws;                         // NSCAN
    int*   offsets  = counts   + NSCAN;                   // NSCAN (offsets[N] valid)
    int*   partials = offsets  + NSCAN;                   // 64
    int*   rank     = partials + 64;                      // n_edges
    int*   edge_src = rank     + n_edges;                 // n_edges + 64 slack
    uint4* hsb      = (uint4*)(edge_src + n_edges + 64);  // (N+1)*8 uint4
    uint4* meanh    = hsb + (size_t)(N_NODES_C + 1) * 8;  // N*8 uint4

    // zero the histogram (ws is poisoned; everything else is fully rewritten)
    hipMemsetAsync(counts, 0, NSCAN * sizeof(int), stream);

    int n8 = n_feat / 8;   // 800000
    convert_fp16<<<(n8 + 8 + 255) / 256, 256, 0, stream>>>(h_src, hsb, n8);

    int nbE2 = ((n_edges + 1) / 2 + 255) / 256;
    edge_hist<<<nbE2, 256, 0, stream>>>(dst, counts, rank, n_edges);
    scan_block<<<NB_SCAN, SCAN_BS, 0, stream>>>(counts, offsets, partials);
    scan_add<<<NB_SCAN, SCAN_BS, 0, stream>>>(offsets, partials);
    edge_fill<<<nbE2, 256, 0, stream>>>(src, dst, rank, offsets, edge_src, n_edges);

    // one wave per node: 100000 waves = 25000 blocks of 256
    sage_gather<<<N_NODES_C / 4, 256, 0, stream>>>(
        hsb, offsets, edge_src, meanh, N_NODES_C);

    sage_gemm<<<(N_NODES_C + 63) / 64, 256, 0, stream>>>(
        h_dst, meanh, weight, bias, out, N_NODES_C);
}

// Round 18
// 128.253 us; speedup vs baseline: 1.7680x; 1.0671x over previous
//
#include <hip/hip_runtime.h>
#include <hip/hip_bf16.h>
#include <hip/hip_fp16.h>

#define N_NODES_C 100000
#define NSCAN     102400
#define NBKT      256        // coarse buckets, key = dst >> 9 (196 used)
#define NBLK      512        // partition blocks

// ---------------------------------------------------------------------------
// fp16 helpers
// ---------------------------------------------------------------------------
union U2H { unsigned u; __half2 h; };

typedef _Float16 h2v __attribute__((ext_vector_type(2)));   // for fdot2
typedef __fp16   p2v __attribute__((ext_vector_type(2)));   // cvt_pkrtz result
union U2HV { unsigned u; h2v h; };
union U2PV { unsigned u; p2v p; };

__device__ __forceinline__ __half2 addp(__half2 a, unsigned u)
{
    U2H c; c.u = u;
    return __hadd2(a, c.h);
}

__device__ __forceinline__ __half2 shfl_xor_h2(__half2 v, int m)
{
    U2H c; c.h = v;
    c.u = (unsigned)__shfl_xor((int)c.u, m, 64);
    return c.h;
}

__device__ __forceinline__ float dot2(unsigned xu, unsigned wu, float c)
{
#if __has_builtin(__builtin_amdgcn_fdot2)
    U2HV a, b;
    a.u = xu; b.u = wu;
    return __builtin_amdgcn_fdot2(a.h, b.h, c, false);
#else
    asm("v_dot2_f32_f16 %0, %1, %2, %0" : "+v"(c) : "v"(xu), "v"(wu));
    return c;
#endif
}

__device__ __forceinline__ uint4 pk8(float4 f0, float4 f1)
{
    U2PV a, b, c, d;
    a.p = __builtin_amdgcn_cvt_pkrtz(f0.x, f0.y);
    b.p = __builtin_amdgcn_cvt_pkrtz(f0.z, f0.w);
    c.p = __builtin_amdgcn_cvt_pkrtz(f1.x, f1.y);
    d.p = __builtin_amdgcn_cvt_pkrtz(f1.z, f1.w);
    return make_uint4(a.u, b.u, c.u, d.u);
}

// h_src f32 -> packed fp16 copy; row N_NODES_C is zeros (pad row)
__global__ __launch_bounds__(256) void convert_fp16(
    const float* __restrict__ x, uint4* __restrict__ y, int n8)
{
    int i = blockIdx.x * 256 + threadIdx.x;
    if (i >= n8 + 8) return;
    if (i >= n8) { y[i] = make_uint4(0u, 0u, 0u, 0u); return; }
    const float4* x4 = reinterpret_cast<const float4*>(x);
    float4 a = x4[i * 2 + 0];
    float4 b = x4[i * 2 + 1];
    U2H c0, c1, c2, c3;
    c0.h = __floats2half2_rn(a.x, a.y);
    c1.h = __floats2half2_rn(a.z, a.w);
    c2.h = __floats2half2_rn(b.x, b.y);
    c3.h = __floats2half2_rn(b.z, b.w);
    uint4 o;
    o.x = c0.u; o.y = c1.u; o.z = c2.u; o.w = c3.u;
    y[i] = o;
}

// ---------------------------------------------------------------------------
// Partition phase A0: per-block LDS histogram of coarse buckets ->
// one global atomic per (block, bucket). No random-line atomics.
// ---------------------------------------------------------------------------
__global__ __launch_bounds__(256) void partA0(
    const int* __restrict__ dst, int* __restrict__ bucket_hist, int n_edges)
{
    __shared__ int h[NBKT];
    int t = threadIdx.x;
    h[t] = 0;
    __syncthreads();
    int chunk = (n_edges + NBLK - 1) / NBLK;
    int start = blockIdx.x * chunk;
    int end   = min(start + chunk, n_edges);
    for (int e = start + t; e < end; e += 256)
        atomicAdd(&h[dst[e] >> 9], 1);
    __syncthreads();
    int c = h[t];
    if (c) atomicAdd(&bucket_hist[t], c);
}

// A1: scan 256 bucket totals -> bucket_base (exclusive) + cursors. 1 block.
__global__ __launch_bounds__(256) void partA1(
    const int* __restrict__ bucket_hist, int* __restrict__ bucket_base,
    int* __restrict__ cursor, int n_edges)
{
    int t = threadIdx.x;
    int v = bucket_hist[t];
    int incl = v;
    #pragma unroll
    for (int off = 1; off < 64; off <<= 1) {
        int u = __shfl_up(incl, off, 64);
        if ((t & 63) >= off) incl += u;
    }
    __shared__ int wsum[4];
    if ((t & 63) == 63) wsum[t >> 6] = incl;
    __syncthreads();
    int add = 0;
    for (int w = 0; w < (t >> 6); ++w) add += wsum[w];
    incl += add;
    int excl = incl - v;
    bucket_base[t] = excl;
    cursor[t] = excl;
    if (t == 255) bucket_base[256] = incl;   // == n_edges
}

// A2: scatter edges into bucket-partitioned packed array.
// packed = (src << 9) | (dst & 511). Per-(block,bucket) runs are contiguous.
__global__ __launch_bounds__(256) void partA2(
    const int* __restrict__ src, const int* __restrict__ dst,
    int* __restrict__ cursor, int* __restrict__ packed, int n_edges)
{
    __shared__ int h[NBKT];
    __shared__ int lcur[NBKT];
    int t = threadIdx.x;
    h[t] = 0;
    __syncthreads();
    int chunk = (n_edges + NBLK - 1) / NBLK;
    int start = blockIdx.x * chunk;
    int end   = min(start + chunk, n_edges);
    for (int e = start + t; e < end; e += 256)
        atomicAdd(&h[dst[e] >> 9], 1);
    __syncthreads();
    int c = h[t];
    int base = 0;
    if (c) base = atomicAdd(&cursor[t], c);   // 1 returning atomic / (blk,bkt)
    lcur[t] = base;
    __syncthreads();
    for (int e = start + t; e < end; e += 256) {
        int d = dst[e];
        int pos = atomicAdd(&lcur[d >> 9], 1);  // LDS returning atomic
        packed[pos] = (src[e] << 9) | (d & 511);
    }
}

// B: one block per bucket (196). LDS count[512] -> scan -> CSR offsets +
// scatter edge_src into the bucket's contiguous region.
__global__ __launch_bounds__(256) void partB(
    const int* __restrict__ packed, const int* __restrict__ bucket_base,
    int* __restrict__ offsets, int* __restrict__ edge_src)
{
    __shared__ int cnt[512];
    __shared__ int sA[512], sB[512];
    int t = threadIdx.x;
    int k = blockIdx.x;
    int b0 = bucket_base[k];
    int b1 = bucket_base[k + 1];

    cnt[t] = 0; cnt[t + 256] = 0;
    __syncthreads();
    for (int i = b0 + t; i < b1; i += 256)
        atomicAdd(&cnt[packed[i] & 511], 1);
    __syncthreads();

    // inclusive Hillis-Steele scan of cnt[512] (ping-pong sA/sB)
    sA[t] = cnt[t]; sA[t + 256] = cnt[t + 256];
    __syncthreads();
    int* pin  = sA;
    int* pout = sB;
    for (int off = 1; off < 512; off <<= 1) {
        int a = pin[t];
        if (t >= off) a += pin[t - off];
        int b = pin[t + 256] + pin[t + 256 - off];   // t+256 >= off always (off<=256)
        pout[t] = a; pout[t + 256] = b;
        __syncthreads();
        int* tmp = pin; pin = pout; pout = tmp;
    }

    // offsets + cursors (overwrite cnt with global cursor start)
    {
        int j0 = t, j1 = t + 256;
        int e0 = pin[j0] - cnt[j0];
        int e1 = pin[j1] - cnt[j1];
        int d0 = k * 512 + j0;
        int d1 = k * 512 + j1;
        offsets[d0] = b0 + e0;
        offsets[d1] = b0 + e1;
        cnt[j0] = b0 + e0;
        cnt[j1] = b0 + e1;
    }
    __syncthreads();

    for (int i = b0 + t; i < b1; i += 256) {
        int p = packed[i];
        int pos = atomicAdd(&cnt[p & 511], 1);   // LDS returning atomic
        edge_src[pos] = p >> 9;
    }
}

// ---------------------------------------------------------------------------
// Gather: ONE WAVE PER NODE. Tail clamp -> zero pad row (index N).
// ---------------------------------------------------------------------------
__global__ __launch_bounds__(256) void sage_gather(
    const uint4* __restrict__ hsb,
    const int*   __restrict__ offsets,
    const int*   __restrict__ edge_src,
    uint4*       __restrict__ meanh,
    int n_nodes)
{
    int wid  = (blockIdx.x * 256 + threadIdx.x) >> 6;
    int lane = threadIdx.x & 63;
    int slot = lane >> 3;
    int chunk = lane & 7;

    int e0  = offsets[wid];
    int e1  = offsets[wid + 1];
    int deg = e1 - e0;
    int nit = (deg + 7) >> 3;

    __half2 a0, a1, a2, a3;
    {
        U2H z; z.u = 0u;
        a0 = z.h; a1 = z.h; a2 = z.h; a3 = z.h;
    }

    for (int it = 0; it < nit; ++it) {
        int idx = e0 + (it << 3) + slot;
        int s = (idx < e1) ? edge_src[idx] : N_NODES_C;
        uint4 v = hsb[(size_t)s * 8 + chunk];
        a0 = addp(a0, v.x);
        a1 = addp(a1, v.y);
        a2 = addp(a2, v.z);
        a3 = addp(a3, v.w);
    }

    #pragma unroll
    for (int m = 8; m < 64; m <<= 1) {
        a0 = __hadd2(a0, shfl_xor_h2(a0, m));
        a1 = __hadd2(a1, shfl_xor_h2(a1, m));
        a2 = __hadd2(a2, shfl_xor_h2(a2, m));
        a3 = __hadd2(a3, shfl_xor_h2(a3, m));
    }

    if (lane < 8) {
        float invd = 1.0f / (float)(deg > 1 ? deg : 1);
        U2H o0, o1, o2, o3;
        o0.h = __floats2half2_rn(__low2float(a0) * invd, __high2float(a0) * invd);
        o1.h = __floats2half2_rn(__low2float(a1) * invd, __high2float(a1) * invd);
        o2.h = __floats2half2_rn(__low2float(a2) * invd, __high2float(a2) * invd);
        o3.h = __floats2half2_rn(__low2float(a3) * invd, __high2float(a3) * invd);
        meanh[(size_t)wid * 8 + lane] = make_uint4(o0.u, o1.u, o2.u, o3.u);
    }
}

// ---------------------------------------------------------------------------
// GEMM epilogue: X and W packed fp16 in LDS (32KB), v_dot2_f32_f16 loop.
// ---------------------------------------------------------------------------
__global__ __launch_bounds__(256) void sage_gemm(
    const float* __restrict__ h_dst,
    const uint4* __restrict__ meanh,
    const float* __restrict__ weight,
    const float* __restrict__ bias,
    float*       __restrict__ out,
    int n_nodes)
{
    __shared__ uint4 xh4[64 * 16];
    __shared__ uint4 wh4[64 * 16];

    const int t    = threadIdx.x;
    const int base = blockIdx.x * 64;

    const float4* w4g = reinterpret_cast<const float4*>(weight);
    const float4* hd4 = reinterpret_cast<const float4*>(h_dst);

    #pragma unroll
    for (int q = 0; q < 4; ++q) {
        int idx = t + q * 256;
        int o   = idx >> 4;
        int c4  = idx & 15;
        float4 f0 = w4g[o * 32 + c4 * 2 + 0];
        float4 f1 = w4g[o * 32 + c4 * 2 + 1];
        wh4[o * 16 + ((c4 + (o >> 2)) & 15)] = pk8(f0, f1);
    }

    #pragma unroll
    for (int q = 0; q < 2; ++q) {
        int idx = t + q * 256;
        int r   = idx >> 3;
        int c4  = idx & 7;
        int g   = base + r;
        float4 f0 = make_float4(0.f, 0.f, 0.f, 0.f);
        float4 f1 = f0;
        if (g < n_nodes) {
            f0 = hd4[(size_t)g * 16 + c4 * 2 + 0];
            f1 = hd4[(size_t)g * 16 + c4 * 2 + 1];
        }
        xh4[r * 16 + ((c4 + r) & 15)] = pk8(f0, f1);
    }

    #pragma unroll
    for (int q = 0; q < 2; ++q) {
        int idx = t + q * 256;
        int r   = idx >> 3;
        int c8  = idx & 7;
        int g   = base + r;
        uint4 mv = make_uint4(0u, 0u, 0u, 0u);
        if (g < n_nodes)
            mv = meanh[(size_t)g * 8 + c8];
        xh4[r * 16 + (((8 + c8) + r) & 15)] = mv;
    }
    __syncthreads();

    const int m  = t & 15;
    const int r0 = t >> 4;
    const int o0 = m * 4;

    float4 bv = reinterpret_cast<const float4*>(bias)[m];

    float acc[4][4];
    #pragma unroll
    for (int i = 0; i < 4; ++i) {
        acc[i][0] = bv.x; acc[i][1] = bv.y; acc[i][2] = bv.z; acc[i][3] = bv.w;
    }

    #pragma unroll 4
    for (int c4 = 0; c4 < 16; ++c4) {
        uint4 wq[4];
        #pragma unroll
        for (int jj = 0; jj < 4; ++jj) {
            int o = o0 + jj;
            wq[jj] = wh4[o * 16 + ((c4 + m) & 15)];
        }
        #pragma unroll
        for (int i = 0; i < 4; ++i) {
            int r = r0 + 16 * i;
            uint4 xq = xh4[r * 16 + ((c4 + r) & 15)];
            #pragma unroll
            for (int jj = 0; jj < 4; ++jj) {
                float a = acc[i][jj];
                a = dot2(xq.x, wq[jj].x, a);
                a = dot2(xq.y, wq[jj].y, a);
                a = dot2(xq.z, wq[jj].z, a);
                a = dot2(xq.w, wq[jj].w, a);
                acc[i][jj] = a;
            }
        }
    }

    #pragma unroll
    for (int i = 0; i < 4; ++i) {
        int g = base + r0 + 16 * i;
        if (g < n_nodes) {
            float4 ov = make_float4(acc[i][0], acc[i][1], acc[i][2], acc[i][3]);
            reinterpret_cast<float4*>(out)[(size_t)g * 16 + m] = ov;
        }
    }
}

// ---------------------------------------------------------------------------
extern "C" void kernel_launch(void* const* d_in, const int* in_sizes, int n_in,
                              void* d_out, int out_size, void* d_ws, size_t ws_size,
                              hipStream_t stream)
{
    const float* h_src  = (const float*)d_in[0];
    const float* h_dst  = (const float*)d_in[1];
    const int*   src    = (const int*)d_in[2];
    const int*   dst    = (const int*)d_in[3];
    const float* weight = (const float*)d_in[4];
    const float* bias   = (const float*)d_in[5];
    float*       out    = (float*)d_out;

    const int n_edges = in_sizes[2];
    const int n_feat  = in_sizes[0];   // N*64 floats

    // workspace layout (ints); hsb base stays 16B-aligned:
    // 256 + 260 + 256 + n_edges + n_edges + 64 = 2,000,836 ints (mult of 4)
    int*   bucket_hist = (int*)d_ws;                    // 256
    int*   bucket_base = bucket_hist + 256;             // 257 (pad to 260)
    int*   cursor      = bucket_base + 260;             // 256
    int*   packed      = cursor + 256;                  // n_edges
    int*   edge_src    = packed + n_edges;              // n_edges + 64 slack
    uint4* hsb         = (uint4*)(edge_src + n_edges + 64);   // (N+1)*8
    uint4* meanh       = hsb + (size_t)(N_NODES_C + 1) * 8;   // N*8
    int*   offsets     = (int*)(meanh + (size_t)N_NODES_C * 8);  // NSCAN

    hipMemsetAsync(bucket_hist, 0, 256 * sizeof(int), stream);

    int n8 = n_feat / 8;   // 800000
    convert_fp16<<<(n8 + 8 + 255) / 256, 256, 0, stream>>>(h_src, hsb, n8);

    partA0<<<NBLK, 256, 0, stream>>>(dst, bucket_hist, n_edges);
    partA1<<<1, 256, 0, stream>>>(bucket_hist, bucket_base, cursor, n_edges);
    partA2<<<NBLK, 256, 0, stream>>>(src, dst, cursor, packed, n_edges);
    partB<<<(N_NODES_C + 511) / 512, 256, 0, stream>>>(
        packed, bucket_base, offsets, edge_src);

    sage_gather<<<N_NODES_C / 4, 256, 0, stream>>>(
        hsb, offsets, edge_src, meanh, N_NODES_C);

    sage_gemm<<<(N_NODES_C + 63) / 64, 256, 0, stream>>>(
        h_dst, meanh, weight, bias, out, N_NODES_C);
}

// Round 19
// 117.791 us; speedup vs baseline: 1.9251x; 1.0888x over previous
//
#include <hip/hip_runtime.h>
#include <hip/hip_bf16.h>
#include <hip/hip_fp16.h>

#define N_NODES_C 100000
#define NSCAN     102400
#define NBKT      256        // coarse buckets, key = dst >> 9 (196 used)
#define NBLK      512        // partition blocks

// ---------------------------------------------------------------------------
// fp16 helpers
// ---------------------------------------------------------------------------
union U2H { unsigned u; __half2 h; };

typedef _Float16 h2v __attribute__((ext_vector_type(2)));   // for fdot2
typedef __fp16   p2v __attribute__((ext_vector_type(2)));   // cvt_pkrtz result
union U2HV { unsigned u; h2v h; };
union U2PV { unsigned u; p2v p; };

__device__ __forceinline__ __half2 addp(__half2 a, unsigned u)
{
    U2H c; c.u = u;
    return __hadd2(a, c.h);
}

__device__ __forceinline__ __half2 shfl_xor_h2(__half2 v, int m)
{
    U2H c; c.h = v;
    c.u = (unsigned)__shfl_xor((int)c.u, m, 64);
    return c.h;
}

__device__ __forceinline__ float dot2(unsigned xu, unsigned wu, float c)
{
#if __has_builtin(__builtin_amdgcn_fdot2)
    U2HV a, b;
    a.u = xu; b.u = wu;
    return __builtin_amdgcn_fdot2(a.h, b.h, c, false);
#else
    asm("v_dot2_f32_f16 %0, %1, %2, %0" : "+v"(c) : "v"(xu), "v"(wu));
    return c;
#endif
}

__device__ __forceinline__ uint4 pk8(float4 f0, float4 f1)
{
    U2PV a, b, c, d;
    a.p = __builtin_amdgcn_cvt_pkrtz(f0.x, f0.y);
    b.p = __builtin_amdgcn_cvt_pkrtz(f0.z, f0.w);
    c.p = __builtin_amdgcn_cvt_pkrtz(f1.x, f1.y);
    d.p = __builtin_amdgcn_cvt_pkrtz(f1.z, f1.w);
    return make_uint4(a.u, b.u, c.u, d.u);
}

// ---------------------------------------------------------------------------
// Fused: h_src f32 -> packed fp16 (blocks [0, nConv)), pad row N = zeros;
// per-block bucket histogram -> count matrix, NO atomics (blocks [nConv, +NBLK)).
// ---------------------------------------------------------------------------
__global__ __launch_bounds__(256) void fusedA0(
    const float* __restrict__ x, uint4* __restrict__ y, int n8,
    const int* __restrict__ dst, int* __restrict__ bucket_cnt, int n_edges,
    int nConv)
{
    __shared__ int h[NBKT];
    int t = threadIdx.x;
    if ((int)blockIdx.x < nConv) {
        int i = blockIdx.x * 256 + t;
        if (i >= n8 + 8) return;
        if (i >= n8) { y[i] = make_uint4(0u, 0u, 0u, 0u); return; }
        const float4* x4 = reinterpret_cast<const float4*>(x);
        float4 a = x4[i * 2 + 0];
        float4 b = x4[i * 2 + 1];
        U2H c0, c1, c2, c3;
        c0.h = __floats2half2_rn(a.x, a.y);
        c1.h = __floats2half2_rn(a.z, a.w);
        c2.h = __floats2half2_rn(b.x, b.y);
        c3.h = __floats2half2_rn(b.z, b.w);
        uint4 o;
        o.x = c0.u; o.y = c1.u; o.z = c2.u; o.w = c3.u;
        y[i] = o;
    } else {
        int blk = blockIdx.x - nConv;
        h[t] = 0;
        __syncthreads();
        int chunk = (n_edges + NBLK - 1) / NBLK;
        int start = blk * chunk;
        int end   = min(start + chunk, n_edges);
        for (int e = start + t; e < end; e += 256)
            atomicAdd(&h[dst[e] >> 9], 1);          // LDS atomic only
        __syncthreads();
        bucket_cnt[blk * NBKT + t] = h[t];          // coalesced write
    }
}

// A1a: bucket totals (column sums of count matrix) -> exclusive bucket_base.
__global__ __launch_bounds__(256) void partA1a(
    const int* __restrict__ bucket_cnt, int* __restrict__ bucket_base)
{
    int t = threadIdx.x;
    int v = 0;
    #pragma unroll 8
    for (int blk = 0; blk < NBLK; ++blk)
        v += bucket_cnt[blk * NBKT + t];            // coalesced across lanes
    int incl = v;
    #pragma unroll
    for (int off = 1; off < 64; off <<= 1) {
        int u = __shfl_up(incl, off, 64);
        if ((t & 63) >= off) incl += u;
    }
    __shared__ int wsum[4];
    if ((t & 63) == 63) wsum[t >> 6] = incl;
    __syncthreads();
    int add = 0;
    for (int w = 0; w < (t >> 6); ++w) add += wsum[w];
    incl += add;
    bucket_base[t] = incl - v;
    if (t == 255) bucket_base[256] = incl;          // == n_edges
}

// A1b: per-bucket exclusive scan over the 512 block counts ->
// blk_base[bucket][blk] (absolute positions). One block per bucket.
__global__ __launch_bounds__(256) void partA1b(
    const int* __restrict__ bucket_cnt, const int* __restrict__ bucket_base,
    int* __restrict__ blk_base)
{
    __shared__ int c[512];
    __shared__ int sA[512], sB[512];
    int t = threadIdx.x;
    int b = blockIdx.x;
    c[t]       = bucket_cnt[t * NBKT + b];
    c[t + 256] = bucket_cnt[(t + 256) * NBKT + b];
    __syncthreads();
    sA[t] = c[t]; sA[t + 256] = c[t + 256];
    __syncthreads();
    int* pin  = sA;
    int* pout = sB;
    for (int off = 1; off < 512; off <<= 1) {
        int a0 = pin[t];
        if (t >= off) a0 += pin[t - off];
        int a1 = pin[t + 256] + pin[t + 256 - off];
        pout[t] = a0; pout[t + 256] = a1;
        __syncthreads();
        int* tmp = pin; pin = pout; pout = tmp;
    }
    int base = bucket_base[b];
    blk_base[b * NBLK + t]       = base + pin[t] - c[t];
    blk_base[b * NBLK + t + 256] = base + pin[t + 256] - c[t + 256];
}

// A2: single-pass scatter. lcur preloaded from blk_base (no global atomics).
// packed = (src << 9) | (dst & 511).
__global__ __launch_bounds__(256) void partA2(
    const int* __restrict__ src, const int* __restrict__ dst,
    const int* __restrict__ blk_base, int* __restrict__ packed, int n_edges)
{
    __shared__ int lcur[NBKT];
    int t = threadIdx.x;
    int blk = blockIdx.x;
    lcur[t] = blk_base[t * NBLK + blk];
    __syncthreads();
    int chunk = (n_edges + NBLK - 1) / NBLK;
    int start = blk * chunk;
    int end   = min(start + chunk, n_edges);
    for (int e = start + t; e < end; e += 256) {
        int d = dst[e];
        int pos = atomicAdd(&lcur[d >> 9], 1);      // LDS returning atomic
        packed[pos] = (src[e] << 9) | (d & 511);
    }
}

// B: one block per bucket. LDS count[512] -> scan -> CSR offsets +
// scatter edge_src into the bucket's contiguous region.
__global__ __launch_bounds__(256) void partB(
    const int* __restrict__ packed, const int* __restrict__ bucket_base,
    int* __restrict__ offsets, int* __restrict__ edge_src)
{
    __shared__ int cnt[512];
    __shared__ int sA[512], sB[512];
    int t = threadIdx.x;
    int k = blockIdx.x;
    int b0 = bucket_base[k];
    int b1 = bucket_base[k + 1];

    cnt[t] = 0; cnt[t + 256] = 0;
    __syncthreads();
    for (int i = b0 + t; i < b1; i += 256)
        atomicAdd(&cnt[packed[i] & 511], 1);
    __syncthreads();

    sA[t] = cnt[t]; sA[t + 256] = cnt[t + 256];
    __syncthreads();
    int* pin  = sA;
    int* pout = sB;
    for (int off = 1; off < 512; off <<= 1) {
        int a = pin[t];
        if (t >= off) a += pin[t - off];
        int b = pin[t + 256] + pin[t + 256 - off];
        pout[t] = a; pout[t + 256] = b;
        __syncthreads();
        int* tmp = pin; pin = pout; pout = tmp;
    }

    {
        int j0 = t, j1 = t + 256;
        int e0 = pin[j0] - cnt[j0];
        int e1 = pin[j1] - cnt[j1];
        offsets[k * 512 + j0] = b0 + e0;
        offsets[k * 512 + j1] = b0 + e1;
        cnt[j0] = b0 + e0;
        cnt[j1] = b0 + e1;
    }
    __syncthreads();

    for (int i = b0 + t; i < b1; i += 256) {
        int p = packed[i];
        int pos = atomicAdd(&cnt[p & 511], 1);
        edge_src[pos] = p >> 9;
    }
}

// ---------------------------------------------------------------------------
// Gather: ONE WAVE PER NODE. Tail clamp -> zero pad row (index N).
// ---------------------------------------------------------------------------
__global__ __launch_bounds__(256) void sage_gather(
    const uint4* __restrict__ hsb,
    const int*   __restrict__ offsets,
    const int*   __restrict__ edge_src,
    uint4*       __restrict__ meanh,
    int n_nodes)
{
    int wid  = (blockIdx.x * 256 + threadIdx.x) >> 6;
    int lane = threadIdx.x & 63;
    int slot = lane >> 3;
    int chunk = lane & 7;

    int e0  = offsets[wid];
    int e1  = offsets[wid + 1];
    int deg = e1 - e0;
    int nit = (deg + 7) >> 3;

    __half2 a0, a1, a2, a3;
    {
        U2H z; z.u = 0u;
        a0 = z.h; a1 = z.h; a2 = z.h; a3 = z.h;
    }

    for (int it = 0; it < nit; ++it) {
        int idx = e0 + (it << 3) + slot;
        int s = (idx < e1) ? edge_src[idx] : N_NODES_C;
        uint4 v = hsb[(size_t)s * 8 + chunk];
        a0 = addp(a0, v.x);
        a1 = addp(a1, v.y);
        a2 = addp(a2, v.z);
        a3 = addp(a3, v.w);
    }

    #pragma unroll
    for (int m = 8; m < 64; m <<= 1) {
        a0 = __hadd2(a0, shfl_xor_h2(a0, m));
        a1 = __hadd2(a1, shfl_xor_h2(a1, m));
        a2 = __hadd2(a2, shfl_xor_h2(a2, m));
        a3 = __hadd2(a3, shfl_xor_h2(a3, m));
    }

    if (lane < 8) {
        float invd = 1.0f / (float)(deg > 1 ? deg : 1);
        U2H o0, o1, o2, o3;
        o0.h = __floats2half2_rn(__low2float(a0) * invd, __high2float(a0) * invd);
        o1.h = __floats2half2_rn(__low2float(a1) * invd, __high2float(a1) * invd);
        o2.h = __floats2half2_rn(__low2float(a2) * invd, __high2float(a2) * invd);
        o3.h = __floats2half2_rn(__low2float(a3) * invd, __high2float(a3) * invd);
        meanh[(size_t)wid * 8 + lane] = make_uint4(o0.u, o1.u, o2.u, o3.u);
    }
}

// ---------------------------------------------------------------------------
// GEMM epilogue: X and W packed fp16 in LDS (32KB), v_dot2_f32_f16 loop.
// ---------------------------------------------------------------------------
__global__ __launch_bounds__(256) void sage_gemm(
    const float* __restrict__ h_dst,
    const uint4* __restrict__ meanh,
    const float* __restrict__ weight,
    const float* __restrict__ bias,
    float*       __restrict__ out,
    int n_nodes)
{
    __shared__ uint4 xh4[64 * 16];
    __shared__ uint4 wh4[64 * 16];

    const int t    = threadIdx.x;
    const int base = blockIdx.x * 64;

    const float4* w4g = reinterpret_cast<const float4*>(weight);
    const float4* hd4 = reinterpret_cast<const float4*>(h_dst);

    #pragma unroll
    for (int q = 0; q < 4; ++q) {
        int idx = t + q * 256;
        int o   = idx >> 4;
        int c4  = idx & 15;
        float4 f0 = w4g[o * 32 + c4 * 2 + 0];
        float4 f1 = w4g[o * 32 + c4 * 2 + 1];
        wh4[o * 16 + ((c4 + (o >> 2)) & 15)] = pk8(f0, f1);
    }

    #pragma unroll
    for (int q = 0; q < 2; ++q) {
        int idx = t + q * 256;
        int r   = idx >> 3;
        int c4  = idx & 7;
        int g   = base + r;
        float4 f0 = make_float4(0.f, 0.f, 0.f, 0.f);
        float4 f1 = f0;
        if (g < n_nodes) {
            f0 = hd4[(size_t)g * 16 + c4 * 2 + 0];
            f1 = hd4[(size_t)g * 16 + c4 * 2 + 1];
        }
        xh4[r * 16 + ((c4 + r) & 15)] = pk8(f0, f1);
    }

    #pragma unroll
    for (int q = 0; q < 2; ++q) {
        int idx = t + q * 256;
        int r   = idx >> 3;
        int c8  = idx & 7;
        int g   = base + r;
        uint4 mv = make_uint4(0u, 0u, 0u, 0u);
        if (g < n_nodes)
            mv = meanh[(size_t)g * 8 + c8];
        xh4[r * 16 + (((8 + c8) + r) & 15)] = mv;
    }
    __syncthreads();

    const int m  = t & 15;
    const int r0 = t >> 4;
    const int o0 = m * 4;

    float4 bv = reinterpret_cast<const float4*>(bias)[m];

    float acc[4][4];
    #pragma unroll
    for (int i = 0; i < 4; ++i) {
        acc[i][0] = bv.x; acc[i][1] = bv.y; acc[i][2] = bv.z; acc[i][3] = bv.w;
    }

    #pragma unroll 4
    for (int c4 = 0; c4 < 16; ++c4) {
        uint4 wq[4];
        #pragma unroll
        for (int jj = 0; jj < 4; ++jj) {
            int o = o0 + jj;
            wq[jj] = wh4[o * 16 + ((c4 + m) & 15)];
        }
        #pragma unroll
        for (int i = 0; i < 4; ++i) {
            int r = r0 + 16 * i;
            uint4 xq = xh4[r * 16 + ((c4 + r) & 15)];
            #pragma unroll
            for (int jj = 0; jj < 4; ++jj) {
                float a = acc[i][jj];
                a = dot2(xq.x, wq[jj].x, a);
                a = dot2(xq.y, wq[jj].y, a);
                a = dot2(xq.z, wq[jj].z, a);
                a = dot2(xq.w, wq[jj].w, a);
                acc[i][jj] = a;
            }
        }
    }

    #pragma unroll
    for (int i = 0; i < 4; ++i) {
        int g = base + r0 + 16 * i;
        if (g < n_nodes) {
            float4 ov = make_float4(acc[i][0], acc[i][1], acc[i][2], acc[i][3]);
            reinterpret_cast<float4*>(out)[(size_t)g * 16 + m] = ov;
        }
    }
}

// ---------------------------------------------------------------------------
extern "C" void kernel_launch(void* const* d_in, const int* in_sizes, int n_in,
                              void* d_out, int out_size, void* d_ws, size_t ws_size,
                              hipStream_t stream)
{
    const float* h_src  = (const float*)d_in[0];
    const float* h_dst  = (const float*)d_in[1];
    const int*   src    = (const int*)d_in[2];
    const int*   dst    = (const int*)d_in[3];
    const float* weight = (const float*)d_in[4];
    const float* bias   = (const float*)d_in[5];
    float*       out    = (float*)d_out;

    const int n_edges = in_sizes[2];
    const int n_feat  = in_sizes[0];   // N*64 floats

    // workspace layout (ints); hsb base 16B-aligned:
    // 131072 + 131072 + 260 + n_edges + n_edges + 64 -> mult of 4
    int*   bucket_cnt  = (int*)d_ws;                    // NBLK*NBKT
    int*   blk_base    = bucket_cnt + NBLK * NBKT;      // NBKT*NBLK
    int*   bucket_base = blk_base + NBKT * NBLK;        // 257 (pad 260)
    int*   packed      = bucket_base + 260;             // n_edges
    int*   edge_src    = packed + n_edges;              // n_edges + 64 slack
    uint4* hsb         = (uint4*)(edge_src + n_edges + 64);   // (N+1)*8
    uint4* meanh       = hsb + (size_t)(N_NODES_C + 1) * 8;   // N*8
    int*   offsets     = (int*)(meanh + (size_t)N_NODES_C * 8);  // NSCAN

    int n8 = n_feat / 8;   // 800000
    int nConv = (n8 + 8 + 255) / 256;

    fusedA0<<<nConv + NBLK, 256, 0, stream>>>(
        h_src, hsb, n8, dst, bucket_cnt, n_edges, nConv);
    partA1a<<<1, 256, 0, stream>>>(bucket_cnt, bucket_base);
    partA1b<<<NBKT, 256, 0, stream>>>(bucket_cnt, bucket_base, blk_base);
    partA2<<<NBLK, 256, 0, stream>>>(src, dst, blk_base, packed, n_edges);
    partB<<<(N_NODES_C + 511) / 512, 256, 0, stream>>>(
        packed, bucket_base, offsets, edge_src);

    sage_gather<<<N_NODES_C / 4, 256, 0, stream>>>(
        hsb, offsets, edge_src, meanh, N_NODES_C);

    sage_gemm<<<(N_NODES_C + 63) / 64, 256, 0, stream>>>(
        h_dst, meanh, weight, bias, out, N_NODES_C);
}

// Round 20
// 106.022 us; speedup vs baseline: 2.1388x; 1.1110x over previous
//
#include <hip/hip_runtime.h>
#include <hip/hip_bf16.h>
#include <hip/hip_fp16.h>

#define N_NODES_C 100000
#define NSCAN     102400
#define NBKT      256        // coarse buckets, key = dst >> 9 (196 used)
#define NBLK      512        // partition blocks

// ---------------------------------------------------------------------------
// fp16 helpers
// ---------------------------------------------------------------------------
union U2H { unsigned u; __half2 h; };

typedef _Float16 h2v __attribute__((ext_vector_type(2)));   // for fdot2
typedef __fp16   p2v __attribute__((ext_vector_type(2)));   // cvt_pkrtz result
union U2HV { unsigned u; h2v h; };
union U2PV { unsigned u; p2v p; };

__device__ __forceinline__ __half2 addp(__half2 a, unsigned u)
{
    U2H c; c.u = u;
    return __hadd2(a, c.h);
}

__device__ __forceinline__ __half2 shfl_xor_h2(__half2 v, int m)
{
    U2H c; c.h = v;
    c.u = (unsigned)__shfl_xor((int)c.u, m, 64);
    return c.h;
}

__device__ __forceinline__ float dot2(unsigned xu, unsigned wu, float c)
{
#if __has_builtin(__builtin_amdgcn_fdot2)
    U2HV a, b;
    a.u = xu; b.u = wu;
    return __builtin_amdgcn_fdot2(a.h, b.h, c, false);
#else
    asm("v_dot2_f32_f16 %0, %1, %2, %0" : "+v"(c) : "v"(xu), "v"(wu));
    return c;
#endif
}

__device__ __forceinline__ uint4 pk8(float4 f0, float4 f1)
{
    U2PV a, b, c, d;
    a.p = __builtin_amdgcn_cvt_pkrtz(f0.x, f0.y);
    b.p = __builtin_amdgcn_cvt_pkrtz(f0.z, f0.w);
    c.p = __builtin_amdgcn_cvt_pkrtz(f1.x, f1.y);
    d.p = __builtin_amdgcn_cvt_pkrtz(f1.z, f1.w);
    return make_uint4(a.u, b.u, c.u, d.u);
}

// chunk per partition block, multiple of 4 so int4 loads stay aligned and
// fusedA0-hist / partA2 cover identical ranges.
__device__ __forceinline__ int part_chunk(int n_edges)
{
    return (((n_edges + NBLK - 1) / NBLK) + 3) & ~3;
}

// ---------------------------------------------------------------------------
// Fused: h_src f32 -> packed fp16 (blocks [0, nConv)), pad row N = zeros;
// per-block bucket histogram (int4 edge loads) -> count matrix, no atomics.
// ---------------------------------------------------------------------------
__global__ __launch_bounds__(256) void fusedA0(
    const float* __restrict__ x, uint4* __restrict__ y, int n8,
    const int* __restrict__ dst, int* __restrict__ bucket_cnt, int n_edges,
    int nConv)
{
    __shared__ int h[NBKT];
    int t = threadIdx.x;
    if ((int)blockIdx.x < nConv) {
        int i = blockIdx.x * 256 + t;
        if (i >= n8 + 8) return;
        if (i >= n8) { y[i] = make_uint4(0u, 0u, 0u, 0u); return; }
        const float4* x4 = reinterpret_cast<const float4*>(x);
        float4 a = x4[i * 2 + 0];
        float4 b = x4[i * 2 + 1];
        U2H c0, c1, c2, c3;
        c0.h = __floats2half2_rn(a.x, a.y);
        c1.h = __floats2half2_rn(a.z, a.w);
        c2.h = __floats2half2_rn(b.x, b.y);
        c3.h = __floats2half2_rn(b.z, b.w);
        uint4 o;
        o.x = c0.u; o.y = c1.u; o.z = c2.u; o.w = c3.u;
        y[i] = o;
    } else {
        int blk = blockIdx.x - nConv;
        h[t] = 0;
        __syncthreads();
        int chunk = part_chunk(n_edges);
        int start = blk * chunk;
        int end   = min(start + chunk, n_edges);
        if (start < end) {
            int nv = (end - start) >> 2;
            const int4* d4 = reinterpret_cast<const int4*>(dst + start);
            for (int k = t; k < nv; k += 256) {
                int4 d = d4[k];
                atomicAdd(&h[d.x >> 9], 1);
                atomicAdd(&h[d.y >> 9], 1);
                atomicAdd(&h[d.z >> 9], 1);
                atomicAdd(&h[d.w >> 9], 1);
            }
            for (int e = start + (nv << 2) + t; e < end; e += 256)
                atomicAdd(&h[dst[e] >> 9], 1);
        }
        __syncthreads();
        bucket_cnt[blk * NBKT + t] = h[t];
    }
}

// A1a: bucket totals (column sums of count matrix) -> exclusive bucket_base.
__global__ __launch_bounds__(256) void partA1a(
    const int* __restrict__ bucket_cnt, int* __restrict__ bucket_base)
{
    int t = threadIdx.x;
    int v = 0;
    #pragma unroll 8
    for (int blk = 0; blk < NBLK; ++blk)
        v += bucket_cnt[blk * NBKT + t];
    int incl = v;
    #pragma unroll
    for (int off = 1; off < 64; off <<= 1) {
        int u = __shfl_up(incl, off, 64);
        if ((t & 63) >= off) incl += u;
    }
    __shared__ int wsum[4];
    if ((t & 63) == 63) wsum[t >> 6] = incl;
    __syncthreads();
    int add = 0;
    for (int w = 0; w < (t >> 6); ++w) add += wsum[w];
    incl += add;
    bucket_base[t] = incl - v;
    if (t == 255) bucket_base[256] = incl;
}

// A1b: per-bucket exclusive scan over the 512 block counts -> blk_base.
__global__ __launch_bounds__(256) void partA1b(
    const int* __restrict__ bucket_cnt, const int* __restrict__ bucket_base,
    int* __restrict__ blk_base)
{
    __shared__ int c[512];
    __shared__ int sA[512], sB[512];
    int t = threadIdx.x;
    int b = blockIdx.x;
    c[t]       = bucket_cnt[t * NBKT + b];
    c[t + 256] = bucket_cnt[(t + 256) * NBKT + b];
    __syncthreads();
    sA[t] = c[t]; sA[t + 256] = c[t + 256];
    __syncthreads();
    int* pin  = sA;
    int* pout = sB;
    for (int off = 1; off < 512; off <<= 1) {
        int a0 = pin[t];
        if (t >= off) a0 += pin[t - off];
        int a1 = pin[t + 256] + pin[t + 256 - off];
        pout[t] = a0; pout[t + 256] = a1;
        __syncthreads();
        int* tmp = pin; pin = pout; pout = tmp;
    }
    int base = bucket_base[b];
    blk_base[b * NBLK + t]       = base + pin[t] - c[t];
    blk_base[b * NBLK + t + 256] = base + pin[t + 256] - c[t + 256];
}

// A2: single-pass scatter with int4 edge loads. No global atomics.
__global__ __launch_bounds__(256) void partA2(
    const int* __restrict__ src, const int* __restrict__ dst,
    const int* __restrict__ blk_base, int* __restrict__ packed, int n_edges)
{
    __shared__ int lcur[NBKT];
    int t = threadIdx.x;
    int blk = blockIdx.x;
    lcur[t] = blk_base[t * NBLK + blk];
    __syncthreads();
    int chunk = part_chunk(n_edges);
    int start = blk * chunk;
    int end   = min(start + chunk, n_edges);
    if (start >= end) return;
    int nv = (end - start) >> 2;
    const int4* d4 = reinterpret_cast<const int4*>(dst + start);
    const int4* s4 = reinterpret_cast<const int4*>(src + start);
    for (int k = t; k < nv; k += 256) {
        int4 d = d4[k];
        int4 s = s4[k];
        int p0 = atomicAdd(&lcur[d.x >> 9], 1);
        packed[p0] = (s.x << 9) | (d.x & 511);
        int p1 = atomicAdd(&lcur[d.y >> 9], 1);
        packed[p1] = (s.y << 9) | (d.y & 511);
        int p2 = atomicAdd(&lcur[d.z >> 9], 1);
        packed[p2] = (s.z << 9) | (d.z & 511);
        int p3 = atomicAdd(&lcur[d.w >> 9], 1);
        packed[p3] = (s.w << 9) | (d.w & 511);
    }
    for (int e = start + (nv << 2) + t; e < end; e += 256) {
        int d = dst[e];
        int pos = atomicAdd(&lcur[d >> 9], 1);
        packed[pos] = (src[e] << 9) | (d & 511);
    }
}

// B: one block per bucket. int4 passes over packed. LDS scan -> CSR offsets
// + scatter edge_src into the bucket's contiguous region.
__global__ __launch_bounds__(256) void partB(
    const int* __restrict__ packed, const int* __restrict__ bucket_base,
    int* __restrict__ offsets, int* __restrict__ edge_src)
{
    __shared__ int cnt[512];
    __shared__ int sA[512], sB[512];
    int t = threadIdx.x;
    int k = blockIdx.x;
    int b0 = bucket_base[k];
    int b1 = bucket_base[k + 1];

    int a0 = (b0 + 3) & ~3;          // aligned vector start
    int a1 = b1 & ~3;                // aligned vector end
    if (a1 < a0) a1 = a0;
    int headlen = min(a0, b1) - b0;  // <= 3
    int nv = (a1 - a0) >> 2;
    const int4* p4 = reinterpret_cast<const int4*>(packed + a0);

    cnt[t] = 0; cnt[t + 256] = 0;
    __syncthreads();
    if (t < headlen) atomicAdd(&cnt[packed[b0 + t] & 511], 1);
    for (int kk = t; kk < nv; kk += 256) {
        int4 p = p4[kk];
        atomicAdd(&cnt[p.x & 511], 1);
        atomicAdd(&cnt[p.y & 511], 1);
        atomicAdd(&cnt[p.z & 511], 1);
        atomicAdd(&cnt[p.w & 511], 1);
    }
    for (int i = a1 + t; i < b1; i += 256)
        atomicAdd(&cnt[packed[i] & 511], 1);
    __syncthreads();

    sA[t] = cnt[t]; sA[t + 256] = cnt[t + 256];
    __syncthreads();
    int* pin  = sA;
    int* pout = sB;
    for (int off = 1; off < 512; off <<= 1) {
        int v0 = pin[t];
        if (t >= off) v0 += pin[t - off];
        int v1 = pin[t + 256] + pin[t + 256 - off];
        pout[t] = v0; pout[t + 256] = v1;
        __syncthreads();
        int* tmp = pin; pin = pout; pout = tmp;
    }

    {
        int j0 = t, j1 = t + 256;
        int e0 = pin[j0] - cnt[j0];
        int e1 = pin[j1] - cnt[j1];
        offsets[k * 512 + j0] = b0 + e0;
        offsets[k * 512 + j1] = b0 + e1;
        cnt[j0] = b0 + e0;
        cnt[j1] = b0 + e1;
    }
    __syncthreads();

    if (t < headlen) {
        int p = packed[b0 + t];
        int pos = atomicAdd(&cnt[p & 511], 1);
        edge_src[pos] = p >> 9;
    }
    for (int kk = t; kk < nv; kk += 256) {
        int4 p = p4[kk];
        int pos;
        pos = atomicAdd(&cnt[p.x & 511], 1); edge_src[pos] = p.x >> 9;
        pos = atomicAdd(&cnt[p.y & 511], 1); edge_src[pos] = p.y >> 9;
        pos = atomicAdd(&cnt[p.z & 511], 1); edge_src[pos] = p.z >> 9;
        pos = atomicAdd(&cnt[p.w & 511], 1); edge_src[pos] = p.w >> 9;
    }
    for (int i = a1 + t; i < b1; i += 256) {
        int p = packed[i];
        int pos = atomicAdd(&cnt[p & 511], 1);
        edge_src[pos] = p >> 9;
    }
}

// ---------------------------------------------------------------------------
// Gather: ONE WAVE PER NODE, 2-deep unrolled edge loop (merges the two
// idx->row latency chains of the common deg~10 / nit=2 case into one batch).
// Tail clamp -> zero pad row (index N).
// ---------------------------------------------------------------------------
__global__ __launch_bounds__(256) void sage_gather(
    const uint4* __restrict__ hsb,
    const int*   __restrict__ offsets,
    const int*   __restrict__ edge_src,
    uint4*       __restrict__ meanh,
    int n_nodes)
{
    int wid  = (blockIdx.x * 256 + threadIdx.x) >> 6;
    int lane = threadIdx.x & 63;
    int slot = lane >> 3;
    int chunk = lane & 7;

    int e0  = offsets[wid];
    int e1  = offsets[wid + 1];
    int deg = e1 - e0;
    int nit = (deg + 7) >> 3;

    __half2 a0, a1, a2, a3;
    {
        U2H z; z.u = 0u;
        a0 = z.h; a1 = z.h; a2 = z.h; a3 = z.h;
    }

    int it = 0;
    for (; it + 2 <= nit; it += 2) {
        int iA = e0 + (it << 3) + slot;
        int iB = iA + 8;
        int sA_ = edge_src[iA];                       // always in-range (it<nit-1)
        int sB_ = (iB < e1) ? edge_src[iB] : N_NODES_C;
        uint4 vA = hsb[(size_t)sA_ * 8 + chunk];
        uint4 vB = hsb[(size_t)sB_ * 8 + chunk];
        a0 = addp(a0, vA.x); a1 = addp(a1, vA.y);
        a2 = addp(a2, vA.z); a3 = addp(a3, vA.w);
        a0 = addp(a0, vB.x); a1 = addp(a1, vB.y);
        a2 = addp(a2, vB.z); a3 = addp(a3, vB.w);
    }
    if (it < nit) {
        int idx = e0 + (it << 3) + slot;
        int s = (idx < e1) ? edge_src[idx] : N_NODES_C;
        uint4 v = hsb[(size_t)s * 8 + chunk];
        a0 = addp(a0, v.x);
        a1 = addp(a1, v.y);
        a2 = addp(a2, v.z);
        a3 = addp(a3, v.w);
    }

    #pragma unroll
    for (int m = 8; m < 64; m <<= 1) {
        a0 = __hadd2(a0, shfl_xor_h2(a0, m));
        a1 = __hadd2(a1, shfl_xor_h2(a1, m));
        a2 = __hadd2(a2, shfl_xor_h2(a2, m));
        a3 = __hadd2(a3, shfl_xor_h2(a3, m));
    }

    if (lane < 8) {
        float invd = 1.0f / (float)(deg > 1 ? deg : 1);
        U2H o0, o1, o2, o3;
        o0.h = __floats2half2_rn(__low2float(a0) * invd, __high2float(a0) * invd);
        o1.h = __floats2half2_rn(__low2float(a1) * invd, __high2float(a1) * invd);
        o2.h = __floats2half2_rn(__low2float(a2) * invd, __high2float(a2) * invd);
        o3.h = __floats2half2_rn(__low2float(a3) * invd, __high2float(a3) * invd);
        meanh[(size_t)wid * 8 + lane] = make_uint4(o0.u, o1.u, o2.u, o3.u);
    }
}

// ---------------------------------------------------------------------------
// GEMM epilogue: X and W packed fp16 in LDS (32KB), v_dot2_f32_f16 loop.
// ---------------------------------------------------------------------------
__global__ __launch_bounds__(256) void sage_gemm(
    const float* __restrict__ h_dst,
    const uint4* __restrict__ meanh,
    const float* __restrict__ weight,
    const float* __restrict__ bias,
    float*       __restrict__ out,
    int n_nodes)
{
    __shared__ uint4 xh4[64 * 16];
    __shared__ uint4 wh4[64 * 16];

    const int t    = threadIdx.x;
    const int base = blockIdx.x * 64;

    const float4* w4g = reinterpret_cast<const float4*>(weight);
    const float4* hd4 = reinterpret_cast<const float4*>(h_dst);

    #pragma unroll
    for (int q = 0; q < 4; ++q) {
        int idx = t + q * 256;
        int o   = idx >> 4;
        int c4  = idx & 15;
        float4 f0 = w4g[o * 32 + c4 * 2 + 0];
        float4 f1 = w4g[o * 32 + c4 * 2 + 1];
        wh4[o * 16 + ((c4 + (o >> 2)) & 15)] = pk8(f0, f1);
    }

    #pragma unroll
    for (int q = 0; q < 2; ++q) {
        int idx = t + q * 256;
        int r   = idx >> 3;
        int c4  = idx & 7;
        int g   = base + r;
        float4 f0 = make_float4(0.f, 0.f, 0.f, 0.f);
        float4 f1 = f0;
        if (g < n_nodes) {
            f0 = hd4[(size_t)g * 16 + c4 * 2 + 0];
            f1 = hd4[(size_t)g * 16 + c4 * 2 + 1];
        }
        xh4[r * 16 + ((c4 + r) & 15)] = pk8(f0, f1);
    }

    #pragma unroll
    for (int q = 0; q < 2; ++q) {
        int idx = t + q * 256;
        int r   = idx >> 3;
        int c8  = idx & 7;
        int g   = base + r;
        uint4 mv = make_uint4(0u, 0u, 0u, 0u);
        if (g < n_nodes)
            mv = meanh[(size_t)g * 8 + c8];
        xh4[r * 16 + (((8 + c8) + r) & 15)] = mv;
    }
    __syncthreads();

    const int m  = t & 15;
    const int r0 = t >> 4;
    const int o0 = m * 4;

    float4 bv = reinterpret_cast<const float4*>(bias)[m];

    float acc[4][4];
    #pragma unroll
    for (int i = 0; i < 4; ++i) {
        acc[i][0] = bv.x; acc[i][1] = bv.y; acc[i][2] = bv.z; acc[i][3] = bv.w;
    }

    #pragma unroll 4
    for (int c4 = 0; c4 < 16; ++c4) {
        uint4 wq[4];
        #pragma unroll
        for (int jj = 0; jj < 4; ++jj) {
            int o = o0 + jj;
            wq[jj] = wh4[o * 16 + ((c4 + m) & 15)];
        }
        #pragma unroll
        for (int i = 0; i < 4; ++i) {
            int r = r0 + 16 * i;
            uint4 xq = xh4[r * 16 + ((c4 + r) & 15)];
            #pragma unroll
            for (int jj = 0; jj < 4; ++jj) {
                float a = acc[i][jj];
                a = dot2(xq.x, wq[jj].x, a);
                a = dot2(xq.y, wq[jj].y, a);
                a = dot2(xq.z, wq[jj].z, a);
                a = dot2(xq.w, wq[jj].w, a);
                acc[i][jj] = a;
            }
        }
    }

    #pragma unroll
    for (int i = 0; i < 4; ++i) {
        int g = base + r0 + 16 * i;
        if (g < n_nodes) {
            float4 ov = make_float4(acc[i][0], acc[i][1], acc[i][2], acc[i][3]);
            reinterpret_cast<float4*>(out)[(size_t)g * 16 + m] = ov;
        }
    }
}

// ---------------------------------------------------------------------------
extern "C" void kernel_launch(void* const* d_in, const int* in_sizes, int n_in,
                              void* d_out, int out_size, void* d_ws, size_t ws_size,
                              hipStream_t stream)
{
    const float* h_src  = (const float*)d_in[0];
    const float* h_dst  = (const float*)d_in[1];
    const int*   src    = (const int*)d_in[2];
    const int*   dst    = (const int*)d_in[3];
    const float* weight = (const float*)d_in[4];
    const float* bias   = (const float*)d_in[5];
    float*       out    = (float*)d_out;

    const int n_edges = in_sizes[2];
    const int n_feat  = in_sizes[0];   // N*64 floats

    // workspace layout (ints); hsb base 16B-aligned
    int*   bucket_cnt  = (int*)d_ws;                    // NBLK*NBKT
    int*   blk_base    = bucket_cnt + NBLK * NBKT;      // NBKT*NBLK
    int*   bucket_base = blk_base + NBKT * NBLK;        // 257 (pad 260)
    int*   packed      = bucket_base + 260;             // n_edges
    int*   edge_src    = packed + n_edges;              // n_edges + 64 slack
    uint4* hsb         = (uint4*)(edge_src + n_edges + 64);   // (N+1)*8
    uint4* meanh       = hsb + (size_t)(N_NODES_C + 1) * 8;   // N*8
    int*   offsets     = (int*)(meanh + (size_t)N_NODES_C * 8);  // NSCAN

    int n8 = n_feat / 8;   // 800000
    int nConv = (n8 + 8 + 255) / 256;

    fusedA0<<<nConv + NBLK, 256, 0, stream>>>(
        h_src, hsb, n8, dst, bucket_cnt, n_edges, nConv);
    partA1a<<<1, 256, 0, stream>>>(bucket_cnt, bucket_base);
    partA1b<<<NBKT, 256, 0, stream>>>(bucket_cnt, bucket_base, blk_base);
    partA2<<<NBLK, 256, 0, stream>>>(src, dst, blk_base, packed, n_edges);
    partB<<<(N_NODES_C + 511) / 512, 256, 0, stream>>>(
        packed, bucket_base, offsets, edge_src);

    sage_gather<<<N_NODES_C / 4, 256, 0, stream>>>(
        hsb, offsets, edge_src, meanh, N_NODES_C);

    sage_gemm<<<(N_NODES_C + 63) / 64, 256, 0, stream>>>(
        h_dst, meanh, weight, bias, out, N_NODES_C);
}